// Round 1
// baseline (1507.275 us; speedup 1.0000x reference)
//
#include <hip/hip_runtime.h>

typedef __attribute__((ext_vector_type(8))) short short8;
typedef __attribute__((ext_vector_type(4))) float f32x4;

#define INF_F __builtin_inff()

__device__ __forceinline__ unsigned short f2bf(float f) {
    unsigned int u = __float_as_uint(f);
    unsigned int r = u + 0x7fffu + ((u >> 16) & 1u);  // RNE
    return (unsigned short)(r >> 16);
}

__device__ __forceinline__ float gelu_exact(float v) {
    return 0.5f * v * (1.0f + erff(v * 0.70710678118654752440f));
}

// ---------------- weight convert: f32 row-major -> bf16 transposed ----------------
__global__ __launch_bounds__(256) void wconv_kernel(
        const float* __restrict__ W1, const float* __restrict__ W2,
        unsigned short* __restrict__ W1t, unsigned short* __restrict__ W2t) {
    int g = blockIdx.x * 256 + threadIdx.x;
    if (g < 65536) {                       // W1: (256,256) -> W1t[c][d]
        int d = g >> 8, c = g & 255;
        W1t[c * 256 + d] = f2bf(W1[g]);
    } else if (g < 98304) {                // W2: (256,128) -> W2t[c][d]
        int g2 = g - 65536;
        int d = g2 >> 7, c = g2 & 127;
        W2t[c * 256 + d] = f2bf(W2[g2]);
    }
}

// ---------------- KNN: exact fp32 d2 replication + lexicographic top-17 ----------------
// 8 partition-threads per query; per-thread sorted top-17 in registers with a
// 4-entry append buffer; 8-way merge in LDS (reusing the points buffer).

#define INSERT(dv, iv) do {                                                       \
    bool rep_ = ((dv) < ld[16]) || ((dv) == ld[16] && (iv) < li[16]);             \
    if (rep_) {                                                                   \
        ld[16] = (dv); li[16] = (iv);                                             \
        _Pragma("unroll")                                                         \
        for (int k2 = 16; k2 > 0; --k2) {                                         \
            bool sw_ = (ld[k2] < ld[k2-1]) ||                                     \
                       (ld[k2] == ld[k2-1] && li[k2] < li[k2-1]);                 \
            float ta_ = sw_ ? ld[k2] : ld[k2-1];                                  \
            float tb_ = sw_ ? ld[k2-1] : ld[k2];                                  \
            int   ia_ = sw_ ? li[k2] : li[k2-1];                                  \
            int   ib_ = sw_ ? li[k2-1] : li[k2];                                  \
            ld[k2-1] = ta_; ld[k2] = tb_; li[k2-1] = ia_; li[k2] = ib_;           \
        }                                                                         \
    } } while (0)

#define LEXPICK(dp, ip, mp) do {                                                  \
    if (((dp) < bd) || ((dp) == bd && (ip) < bi)) { bd = (dp); bi = (ip); bm = (mp); } \
    } while (0)

#define ADVANCE(P, hP, dP, iP) do {                                               \
    if (bm == (P)) {                                                              \
        hP++;                                                                     \
        float2 v_;                                                                \
        if (hP < 17) v_ = lst[lbase + (P)*17 + hP];                               \
        else { v_.x = INF_F; v_.y = __int_as_float(0x7fffffff); }                 \
        dP = v_.x; iP = __float_as_int(v_.y);                                     \
    } } while (0)

__global__ __launch_bounds__(256) void knn_kernel(
        const float* __restrict__ points, int* __restrict__ idx_out) {
    __shared__ float2 sp[8192];            // 64 KB: all points
    const int tid = threadIdx.x;

    // stage points
    const float4* p4 = (const float4*)points;
    float4* s4 = (float4*)sp;
#pragma unroll
    for (int t = 0; t < 16; ++t) s4[tid + 256 * t] = p4[tid + 256 * t];
    __syncthreads();

    const int g    = blockIdx.x * 256 + tid;
    const int q    = g >> 3;               // query id
    const int part = g & 7;                // partition 0..7 (1024 points each)
    const int base = part << 10;

    const float2 qp  = sp[q];
    const float  xi  = qp.x, yi = qp.y;
    const float  sqi = __fadd_rn(__fmul_rn(xi, xi), __fmul_rn(yi, yi));

    float ld[17]; int li[17];
#pragma unroll
    for (int t = 0; t < 17; ++t) { ld[t] = INF_F; li[t] = 0x7fffffff; }

    float bd0 = 0.f, bd1 = 0.f, bd2 = 0.f, bd3 = 0.f;
    int   bi0 = 0, bi1 = 0, bi2 = 0, bi3 = 0;
    int   cnt = 0;
    const int skew = part << 1;            // de-conflict LDS banks across partitions

    for (int j = 0; j < 1024; ++j) {
        const int jj = (j + skew) & 1023;
        const float2 p = sp[base + jj];
        // exact replication of reference fp32 arithmetic:
        const float sqj = __fadd_rn(__fmul_rn(p.x, p.x), __fmul_rn(p.y, p.y));
        const float t   = fmaf(yi, p.y, __fmul_rn(xi, p.x));
        const float s   = __fadd_rn(sqi, sqj);
        const float d2  = fmaf(-2.0f, t, s);
        const int cidx  = base + jj;

        const bool take = (d2 < ld[16]) || (d2 == ld[16] && cidx < li[16]);
        if (take) {
            if      (cnt == 0) { bd0 = d2; bi0 = cidx; }
            else if (cnt == 1) { bd1 = d2; bi1 = cidx; }
            else if (cnt == 2) { bd2 = d2; bi2 = cidx; }
            else               { bd3 = d2; bi3 = cidx; }
            cnt++;
        }
        if (__any(cnt >= 4)) {
            if (cnt > 0) INSERT(bd0, bi0);
            if (cnt > 1) INSERT(bd1, bi1);
            if (cnt > 2) INSERT(bd2, bi2);
            if (cnt > 3) INSERT(bd3, bi3);
            cnt = 0;
        }
    }
    if (cnt > 0) INSERT(bd0, bi0);
    if (cnt > 1) INSERT(bd1, bi1);
    if (cnt > 2) INSERT(bd2, bi2);
    if (cnt > 3) INSERT(bd3, bi3);

    __syncthreads();                        // all reads of sp done
    float2* lst = sp;                       // reuse LDS for the partial lists
#pragma unroll
    for (int t = 0; t < 17; ++t) {
        float2 e; e.x = ld[t]; e.y = __int_as_float(li[t]);
        lst[tid * 17 + t] = e;
    }
    __syncthreads();

    if ((tid & 7) == 0) {                   // one merger per query
        const int lbase = tid * 17;
        int h0 = 0, h1 = 0, h2 = 0, h3 = 0, h4 = 0, h5 = 0, h6 = 0, h7 = 0;
        float2 v;
        v = lst[lbase + 0 * 17];  float d0 = v.x; int i0 = __float_as_int(v.y);
        v = lst[lbase + 1 * 17];  float d1 = v.x; int i1 = __float_as_int(v.y);
        v = lst[lbase + 2 * 17];  float d2v = v.x; int i2 = __float_as_int(v.y);
        v = lst[lbase + 3 * 17];  float d3 = v.x; int i3 = __float_as_int(v.y);
        v = lst[lbase + 4 * 17];  float d4 = v.x; int i4 = __float_as_int(v.y);
        v = lst[lbase + 5 * 17];  float d5 = v.x; int i5 = __float_as_int(v.y);
        v = lst[lbase + 6 * 17];  float d6 = v.x; int i6 = __float_as_int(v.y);
        v = lst[lbase + 7 * 17];  float d7 = v.x; int i7 = __float_as_int(v.y);
#pragma unroll 1
        for (int pick = 0; pick < 17; ++pick) {
            float bd = d0; int bi = i0; int bm = 0;
            LEXPICK(d1, i1, 1); LEXPICK(d2v, i2, 2); LEXPICK(d3, i3, 3);
            LEXPICK(d4, i4, 4); LEXPICK(d5, i5, 5); LEXPICK(d6, i6, 6);
            LEXPICK(d7, i7, 7);
            if (pick > 0) idx_out[q * 16 + pick - 1] = bi;  // drop overall nearest (self)
            ADVANCE(0, h0, d0, i0); ADVANCE(1, h1, d1, i1);
            ADVANCE(2, h2, d2v, i2); ADVANCE(3, h3, d3, i3);
            ADVANCE(4, h4, d4, i4); ADVANCE(5, h5, d5, i5);
            ADVANCE(6, h6, d6, i6); ADVANCE(7, h7, d7, i7);
        }
    }
}

// ---------------- fused gather + MLP + mean, bf16 MFMA ----------------
// block = 4 queries (64 rows), 256 threads (4 waves).
// wave w: mat1 cols [64w,64w+64) as 4x4 tiles of 16x16x32; mat2 cols [32w,32w+32).
__global__ __launch_bounds__(256) void mlp_kernel(
        const float* __restrict__ x,
        const unsigned short* __restrict__ W1t, const float* __restrict__ b1,
        const unsigned short* __restrict__ W2t, const float* __restrict__ b2,
        const int* __restrict__ idx, float* __restrict__ out) {
    __shared__ unsigned short sh[64 * 264];   // padded stride 264 (+8) vs 256
    const int tid = threadIdx.x;
    const int qb  = blockIdx.x << 2;          // first query of this block

    // Phase 0: build local features [knn-center | center] as bf16 in LDS
    {
        const int r   = tid >> 2;             // row 0..63  (= q*16 + k)
        const int seg = tid & 3;              // 32-feature segment
        const int gq  = qb + (r >> 4);
        const int nb  = idx[(gq << 4) + (r & 15)];
        const float* xc = x + gq * 128 + seg * 32;
        const float* xn = x + nb * 128 + seg * 32;
        unsigned short* fr = sh + r * 264;
#pragma unroll
        for (int u = 0; u < 8; ++u) {
            float4 a = ((const float4*)xn)[u];
            float4 c = ((const float4*)xc)[u];
            int d = seg * 32 + u * 4;
            uint2 w0, w1;
            w0.x = (unsigned)f2bf(a.x - c.x) | ((unsigned)f2bf(a.y - c.y) << 16);
            w0.y = (unsigned)f2bf(a.z - c.z) | ((unsigned)f2bf(a.w - c.w) << 16);
            w1.x = (unsigned)f2bf(c.x) | ((unsigned)f2bf(c.y) << 16);
            w1.y = (unsigned)f2bf(c.z) | ((unsigned)f2bf(c.w) << 16);
            *(uint2*)(fr + d)       = w0;
            *(uint2*)(fr + 128 + d) = w1;
        }
    }
    __syncthreads();

    const int lane = tid & 63, wv = tid >> 6;
    const int m = lane & 15, quad = lane >> 4;
    const int ko0 = quad * 8;

    // Phase 1: h1 = gelu(local @ W1 + b1)   (64x256 = 4 row-tiles x 4 col-tiles/wave)
    f32x4 acc[16];
#pragma unroll
    for (int i = 0; i < 16; ++i) acc[i] = (f32x4){0.f, 0.f, 0.f, 0.f};
#pragma unroll
    for (int ks = 0; ks < 8; ++ks) {
        const int ko = ks * 32 + ko0;
        short8 af[4], bfr[4];
#pragma unroll
        for (int rt = 0; rt < 4; ++rt)
            af[rt] = *(const short8*)(sh + (rt * 16 + m) * 264 + ko);
#pragma unroll
        for (int ct = 0; ct < 4; ++ct)
            bfr[ct] = *(const short8*)(W1t + (wv * 64 + ct * 16 + m) * 256 + ko);
#pragma unroll
        for (int rt = 0; rt < 4; ++rt)
#pragma unroll
            for (int ct = 0; ct < 4; ++ct)
                acc[rt * 4 + ct] = __builtin_amdgcn_mfma_f32_16x16x32_bf16(
                    af[rt], bfr[ct], acc[rt * 4 + ct], 0, 0, 0);
    }
    __syncthreads();   // all reads of features complete before overwrite

    // Epilogue 1: bias + exact gelu -> bf16 back into LDS (C/D: row=quad*4+j, col=m)
#pragma unroll
    for (int ct = 0; ct < 4; ++ct) {
        const int col = wv * 64 + ct * 16 + m;
        const float bias = b1[col];
#pragma unroll
        for (int rt = 0; rt < 4; ++rt) {
#pragma unroll
            for (int j = 0; j < 4; ++j) {
                float vv = acc[rt * 4 + ct][j] + bias;
                sh[(rt * 16 + quad * 4 + j) * 264 + col] = f2bf(gelu_exact(vv));
            }
        }
    }
    __syncthreads();

    // Phase 2: h2 = gelu(h1 @ W2 + b2)  (64x128 = 4 row-tiles x 2 col-tiles/wave)
    f32x4 acc2[8];
#pragma unroll
    for (int i = 0; i < 8; ++i) acc2[i] = (f32x4){0.f, 0.f, 0.f, 0.f};
#pragma unroll
    for (int ks = 0; ks < 8; ++ks) {
        const int ko = ks * 32 + ko0;
        short8 af[4], bfr[2];
#pragma unroll
        for (int rt = 0; rt < 4; ++rt)
            af[rt] = *(const short8*)(sh + (rt * 16 + m) * 264 + ko);
#pragma unroll
        for (int ct = 0; ct < 2; ++ct)
            bfr[ct] = *(const short8*)(W2t + (wv * 32 + ct * 16 + m) * 256 + ko);
#pragma unroll
        for (int rt = 0; rt < 4; ++rt)
#pragma unroll
            for (int ct = 0; ct < 2; ++ct)
                acc2[rt * 2 + ct] = __builtin_amdgcn_mfma_f32_16x16x32_bf16(
                    af[rt], bfr[ct], acc2[rt * 2 + ct], 0, 0, 0);
    }

    // Epilogue 2: bias + gelu, mean over K=16 (4 regs + quad reduction), store f32
#pragma unroll
    for (int ct = 0; ct < 2; ++ct) {
        const int col = wv * 32 + ct * 16 + m;
        const float bias = b2[col];
#pragma unroll
        for (int rt = 0; rt < 4; ++rt) {
            float s = 0.f;
#pragma unroll
            for (int j = 0; j < 4; ++j)
                s += gelu_exact(acc2[rt * 2 + ct][j] + bias);
            s += __shfl_xor(s, 16, 64);
            s += __shfl_xor(s, 32, 64);
            if (quad == 0) out[(qb + rt) * 128 + col] = s * 0.0625f;
        }
    }
}

extern "C" void kernel_launch(void* const* d_in, const int* in_sizes, int n_in,
                              void* d_out, int out_size, void* d_ws, size_t ws_size,
                              hipStream_t stream) {
    const float* x      = (const float*)d_in[0];   // (1,8192,128)
    const float* points = (const float*)d_in[1];   // (1,8192,2)
    const float* W1     = (const float*)d_in[2];   // (256,256)
    const float* b1     = (const float*)d_in[3];   // (256,)
    const float* W2     = (const float*)d_in[4];   // (256,128)
    const float* b2     = (const float*)d_in[5];   // (128,)
    // d_in[6] = K (fixed 16)
    float* out = (float*)d_out;

    char* ws = (char*)d_ws;
    unsigned short* W1t = (unsigned short*)ws;                 // 131072 B
    unsigned short* W2t = (unsigned short*)(ws + 131072);      //  65536 B
    int*            idx = (int*)(ws + 196608);                 // 524288 B

    wconv_kernel<<<384, 256, 0, stream>>>(W1, W2, W1t, W2t);
    knn_kernel<<<256, 256, 0, stream>>>(points, idx);
    mlp_kernel<<<2048, 256, 0, stream>>>(x, W1t, b1, W2t, b2, idx, out);
}

// Round 2
// 234.738 us; speedup vs baseline: 6.4211x; 6.4211x over previous
//
#include <hip/hip_runtime.h>

typedef __attribute__((ext_vector_type(8))) short short8;
typedef __attribute__((ext_vector_type(4))) float f32x4;

__device__ __forceinline__ unsigned short f2bf(float f) {
    unsigned int u = __float_as_uint(f);
    unsigned int r = u + 0x7fffu + ((u >> 16) & 1u);  // RNE
    return (unsigned short)(r >> 16);
}

__device__ __forceinline__ float gelu_exact(float v) {
    return 0.5f * v * (1.0f + erff(v * 0.70710678118654752440f));
}

// ---------------- weight convert: f32 row-major -> bf16 transposed ----------------
__global__ __launch_bounds__(256) void wconv_kernel(
        const float* __restrict__ W1, const float* __restrict__ W2,
        unsigned short* __restrict__ W1t, unsigned short* __restrict__ W2t) {
    int g = blockIdx.x * 256 + threadIdx.x;
    if (g < 65536) {                       // W1: (256,256) -> W1t[c][d]
        int d = g >> 8, c = g & 255;
        W1t[c * 256 + d] = f2bf(W1[g]);
    } else if (g < 98304) {                // W2: (256,128) -> W2t[c][d]
        int g2 = g - 65536;
        int d = g2 >> 7, c = g2 & 127;
        W2t[c * 256 + d] = f2bf(W2[g2]);
    }
}

// ---------------- KNN v2: two-scan threshold selection, 1 wave = 1 query ----------------
// Exact replication of reference fp32 d2 arithmetic (same ops as the R1-passing kernel).
// key transform maps float ordering -> unsigned ordering (handles tiny negative d2).

__device__ __forceinline__ unsigned int d2key(float d2) {
    unsigned int u = __float_as_uint(d2);
    return u ^ (((unsigned int)(((int)u) >> 31)) | 0x80000000u);
}

#define U64MAX 0xFFFFFFFFFFFFFFFFull

__global__ __launch_bounds__(256) void knn_kernel(
        const float* __restrict__ points, int* __restrict__ idx_out) {
    __shared__ unsigned long long cand[4][128];
    __shared__ int ccnt[4];

    const int tid  = threadIdx.x;
    const int wv   = tid >> 6;
    const int lane = tid & 63;
    const int q    = (blockIdx.x << 2) + wv;

    const float xi = points[q * 2 + 0];
    const float yi = points[q * 2 + 1];
    const float sqi = __fadd_rn(__fmul_rn(xi, xi), __fmul_rn(yi, yi));

    const float2* pts = (const float2*)points;

    // ---- scan 1: per-lane minimum over its 128 strided points ----
    unsigned long long vmin = U64MAX;
#pragma unroll 4
    for (int j = 0; j < 128; ++j) {
        const int idx = j * 64 + lane;
        const float2 p = pts[idx];
        const float sqj = __fadd_rn(__fmul_rn(p.x, p.x), __fmul_rn(p.y, p.y));
        const float t   = fmaf(yi, p.y, __fmul_rn(xi, p.x));
        const float s   = __fadd_rn(sqi, sqj);
        const float d2  = fmaf(-2.0f, t, s);
        unsigned long long pk = ((unsigned long long)d2key(d2) << 32) | (unsigned int)idx;
        vmin = (pk < vmin) ? pk : vmin;
    }

    // ---- bitonic sort of 64 lane-minima (ascending across lanes) ----
    unsigned long long v = vmin;
#pragma unroll
    for (int k = 2; k <= 64; k <<= 1) {
#pragma unroll
        for (int j = k >> 1; j > 0; j >>= 1) {
            unsigned long long pv = __shfl_xor(v, j, 64);
            const bool up = ((lane & k) == 0);
            const bool low = ((lane & j) == 0);
            const bool takeMin = (up == low);
            const unsigned long long mn = (v < pv) ? v : pv;
            const unsigned long long mx = (v < pv) ? pv : v;
            v = takeMin ? mn : mx;
        }
    }
    const unsigned long long T64 = __shfl(v, 16, 64);   // 17th smallest lane-min
    const unsigned int Tkey = (unsigned int)(T64 >> 32);

    if (lane == 0) ccnt[wv] = 0;
    __syncthreads();

    // ---- scan 2: collect all candidates with key <= Tkey (expected ~20) ----
#pragma unroll 4
    for (int j = 0; j < 128; ++j) {
        const int idx = j * 64 + lane;
        const float2 p = pts[idx];
        const float sqj = __fadd_rn(__fmul_rn(p.x, p.x), __fmul_rn(p.y, p.y));
        const float t   = fmaf(yi, p.y, __fmul_rn(xi, p.x));
        const float s   = __fadd_rn(sqi, sqj);
        const float d2  = fmaf(-2.0f, t, s);
        const unsigned int key = d2key(d2);
        if (key <= Tkey) {
            int pos = atomicAdd(&ccnt[wv], 1);
            if (pos < 128)
                cand[wv][pos] = ((unsigned long long)key << 32) | (unsigned int)idx;
        }
    }
    __syncthreads();

    // ---- extract 17 lexicographic minima; pick 0 is the dropped self/argmin ----
    const int n = ccnt[wv] < 128 ? ccnt[wv] : 128;
    unsigned long long v0 = (lane < n)      ? cand[wv][lane]      : U64MAX;
    unsigned long long v1 = (lane + 64 < n) ? cand[wv][lane + 64] : U64MAX;

#pragma unroll 1
    for (int pick = 0; pick < 17; ++pick) {
        unsigned long long m = (v0 < v1) ? v0 : v1;
#pragma unroll
        for (int d = 1; d < 64; d <<= 1) {
            unsigned long long pm = __shfl_xor(m, d, 64);
            m = (pm < m) ? pm : m;
        }
        if (pick > 0 && lane == 0)
            idx_out[q * 16 + pick - 1] = (int)(unsigned int)(m & 0xFFFFFFFFull);
        if (v0 == m) v0 = U64MAX;
        else if (v1 == m) v1 = U64MAX;
    }
}

// ---------------- fused gather + MLP + mean, bf16 MFMA ----------------
// block = 4 queries (64 rows), 256 threads (4 waves).
// wave w: mat1 cols [64w,64w+64) as 4x4 tiles of 16x16x32; mat2 cols [32w,32w+32).
__global__ __launch_bounds__(256) void mlp_kernel(
        const float* __restrict__ x,
        const unsigned short* __restrict__ W1t, const float* __restrict__ b1,
        const unsigned short* __restrict__ W2t, const float* __restrict__ b2,
        const int* __restrict__ idx, float* __restrict__ out) {
    __shared__ unsigned short sh[64 * 264];   // padded stride 264 (+8) vs 256
    const int tid = threadIdx.x;
    const int qb  = blockIdx.x << 2;          // first query of this block

    // Phase 0: build local features [knn-center | center] as bf16 in LDS
    {
        const int r   = tid >> 2;             // row 0..63  (= q*16 + k)
        const int seg = tid & 3;              // 32-feature segment
        const int gq  = qb + (r >> 4);
        const int nb  = idx[(gq << 4) + (r & 15)];
        const float* xc = x + gq * 128 + seg * 32;
        const float* xn = x + nb * 128 + seg * 32;
        unsigned short* fr = sh + r * 264;
#pragma unroll
        for (int u = 0; u < 8; ++u) {
            float4 a = ((const float4*)xn)[u];
            float4 c = ((const float4*)xc)[u];
            int d = seg * 32 + u * 4;
            uint2 w0, w1;
            w0.x = (unsigned)f2bf(a.x - c.x) | ((unsigned)f2bf(a.y - c.y) << 16);
            w0.y = (unsigned)f2bf(a.z - c.z) | ((unsigned)f2bf(a.w - c.w) << 16);
            w1.x = (unsigned)f2bf(c.x) | ((unsigned)f2bf(c.y) << 16);
            w1.y = (unsigned)f2bf(c.z) | ((unsigned)f2bf(c.w) << 16);
            *(uint2*)(fr + d)       = w0;
            *(uint2*)(fr + 128 + d) = w1;
        }
    }
    __syncthreads();

    const int lane = tid & 63, wv = tid >> 6;
    const int m = lane & 15, quad = lane >> 4;
    const int ko0 = quad * 8;

    // Phase 1: h1 = gelu(local @ W1 + b1)   (64x256 = 4 row-tiles x 4 col-tiles/wave)
    f32x4 acc[16];
#pragma unroll
    for (int i = 0; i < 16; ++i) acc[i] = (f32x4){0.f, 0.f, 0.f, 0.f};
#pragma unroll
    for (int ks = 0; ks < 8; ++ks) {
        const int ko = ks * 32 + ko0;
        short8 af[4], bfr[4];
#pragma unroll
        for (int rt = 0; rt < 4; ++rt)
            af[rt] = *(const short8*)(sh + (rt * 16 + m) * 264 + ko);
#pragma unroll
        for (int ct = 0; ct < 4; ++ct)
            bfr[ct] = *(const short8*)(W1t + (wv * 64 + ct * 16 + m) * 256 + ko);
#pragma unroll
        for (int rt = 0; rt < 4; ++rt)
#pragma unroll
            for (int ct = 0; ct < 4; ++ct)
                acc[rt * 4 + ct] = __builtin_amdgcn_mfma_f32_16x16x32_bf16(
                    af[rt], bfr[ct], acc[rt * 4 + ct], 0, 0, 0);
    }
    __syncthreads();   // all reads of features complete before overwrite

    // Epilogue 1: bias + exact gelu -> bf16 back into LDS (C/D: row=quad*4+j, col=m)
#pragma unroll
    for (int ct = 0; ct < 4; ++ct) {
        const int col = wv * 64 + ct * 16 + m;
        const float bias = b1[col];
#pragma unroll
        for (int rt = 0; rt < 4; ++rt) {
#pragma unroll
            for (int j = 0; j < 4; ++j) {
                float vv = acc[rt * 4 + ct][j] + bias;
                sh[(rt * 16 + quad * 4 + j) * 264 + col] = f2bf(gelu_exact(vv));
            }
        }
    }
    __syncthreads();

    // Phase 2: h2 = gelu(h1 @ W2 + b2)  (64x128 = 4 row-tiles x 2 col-tiles/wave)
    f32x4 acc2[8];
#pragma unroll
    for (int i = 0; i < 8; ++i) acc2[i] = (f32x4){0.f, 0.f, 0.f, 0.f};
#pragma unroll
    for (int ks = 0; ks < 8; ++ks) {
        const int ko = ks * 32 + ko0;
        short8 af[4], bfr[2];
#pragma unroll
        for (int rt = 0; rt < 4; ++rt)
            af[rt] = *(const short8*)(sh + (rt * 16 + m) * 264 + ko);
#pragma unroll
        for (int ct = 0; ct < 2; ++ct)
            bfr[ct] = *(const short8*)(W2t + (wv * 32 + ct * 16 + m) * 256 + ko);
#pragma unroll
        for (int rt = 0; rt < 4; ++rt)
#pragma unroll
            for (int ct = 0; ct < 2; ++ct)
                acc2[rt * 2 + ct] = __builtin_amdgcn_mfma_f32_16x16x32_bf16(
                    af[rt], bfr[ct], acc2[rt * 2 + ct], 0, 0, 0);
    }

    // Epilogue 2: bias + gelu, mean over K=16 (4 regs + quad reduction), store f32
#pragma unroll
    for (int ct = 0; ct < 2; ++ct) {
        const int col = wv * 32 + ct * 16 + m;
        const float bias = b2[col];
#pragma unroll
        for (int rt = 0; rt < 4; ++rt) {
            float s = 0.f;
#pragma unroll
            for (int j = 0; j < 4; ++j)
                s += gelu_exact(acc2[rt * 2 + ct][j] + bias);
            s += __shfl_xor(s, 16, 64);
            s += __shfl_xor(s, 32, 64);
            if (quad == 0) out[(qb + rt) * 128 + col] = s * 0.0625f;
        }
    }
}

extern "C" void kernel_launch(void* const* d_in, const int* in_sizes, int n_in,
                              void* d_out, int out_size, void* d_ws, size_t ws_size,
                              hipStream_t stream) {
    const float* x      = (const float*)d_in[0];   // (1,8192,128)
    const float* points = (const float*)d_in[1];   // (1,8192,2)
    const float* W1     = (const float*)d_in[2];   // (256,256)
    const float* b1     = (const float*)d_in[3];   // (256,)
    const float* W2     = (const float*)d_in[4];   // (256,128)
    const float* b2     = (const float*)d_in[5];   // (128,)
    // d_in[6] = K (fixed 16)
    float* out = (float*)d_out;

    char* ws = (char*)d_ws;
    unsigned short* W1t = (unsigned short*)ws;                 // 131072 B
    unsigned short* W2t = (unsigned short*)(ws + 131072);      //  65536 B
    int*            idx = (int*)(ws + 196608);                 // 524288 B

    wconv_kernel<<<384, 256, 0, stream>>>(W1, W2, W1t, W2t);
    knn_kernel<<<2048, 256, 0, stream>>>(points, idx);
    mlp_kernel<<<2048, 256, 0, stream>>>(x, W1t, b1, W2t, b2, idx, out);
}

// Round 3
// 157.872 us; speedup vs baseline: 9.5474x; 1.4869x over previous
//
#include <hip/hip_runtime.h>

typedef __attribute__((ext_vector_type(8))) short short8;
typedef __attribute__((ext_vector_type(4))) float f32x4;

__device__ __forceinline__ unsigned short f2bf(float f) {
    unsigned int u = __float_as_uint(f);
    unsigned int r = u + 0x7fffu + ((u >> 16) & 1u);  // RNE
    return (unsigned short)(r >> 16);
}

__device__ __forceinline__ float bf2f(short s) {
    return __uint_as_float(((unsigned int)(unsigned short)s) << 16);
}

// tanh-form gelu: x * sigmoid(2*sqrt(2/pi)*(x + 0.044715 x^3)); max dev from
// exact erf-gelu ~3e-4 << bf16 noise. exp2/rcp are single HW instructions.
__device__ __forceinline__ float gelu_fast(float v) {
    float x2 = v * v;
    float s  = v * fmaf(-0.102943195f, x2, -2.3022077f);   // -2z*log2(e)
    float e  = __builtin_amdgcn_exp2f(s);
    return v * __builtin_amdgcn_rcpf(1.0f + e);
}

// ---------------- weight convert: f32 row-major -> bf16 transposed ----------------
__global__ __launch_bounds__(256) void wconv_kernel(
        const float* __restrict__ W1, const float* __restrict__ W2,
        unsigned short* __restrict__ W1t, unsigned short* __restrict__ W2t) {
    int g = blockIdx.x * 256 + threadIdx.x;
    if (g < 65536) {                       // W1: (256,256) -> W1t[c][d]
        int d = g >> 8, c = g & 255;
        W1t[c * 256 + d] = f2bf(W1[g]);
    } else if (g < 98304) {                // W2: (256,128) -> W2t[c][d]
        int g2 = g - 65536;
        int d = g2 >> 7, c = g2 & 127;
        W2t[c * 256 + d] = f2bf(W2[g2]);
    }
}

// ---------------- precompute A = x@W1[:128], D = x@W1[128:] - A + b1 (bf16) -------
// block = 64 x-rows, 256 threads; wave w covers 64 cols as 4x4 16x16 tiles, K=128.
__global__ __launch_bounds__(256) void gemmAD_kernel(
        const float* __restrict__ x, const unsigned short* __restrict__ W1t,
        const float* __restrict__ b1,
        unsigned short* __restrict__ Abf, unsigned short* __restrict__ Dbf) {
    __shared__ unsigned short sx[64 * 136];    // 64 rows x 128 bf16, stride 136
    const int tid = threadIdx.x;
    const int rb  = blockIdx.x * 64;

    {   // stage x rows -> bf16 LDS
        const int r   = ((tid >> 6) << 4) | (tid & 15);   // row 0..63
        const int seg = (tid >> 4) & 3;                   // 32-float segment
        const float* xr = x + (rb + r) * 128 + seg * 32;
        unsigned short* dst = sx + r * 136 + seg * 32;
#pragma unroll
        for (int u = 0; u < 8; ++u) {
            float4 a = ((const float4*)xr)[u];
            uint2 w;
            w.x = (unsigned)f2bf(a.x) | ((unsigned)f2bf(a.y) << 16);
            w.y = (unsigned)f2bf(a.z) | ((unsigned)f2bf(a.w) << 16);
            *(uint2*)(dst + u * 4) = w;
        }
    }
    __syncthreads();

    const int lane = tid & 63, wv = tid >> 6;
    const int m = lane & 15, quad = lane >> 4;
    const int ko0 = quad * 8;

    f32x4 accA[16], accC[16];
#pragma unroll
    for (int i = 0; i < 16; ++i) { accA[i] = (f32x4){0,0,0,0}; accC[i] = (f32x4){0,0,0,0}; }

#pragma unroll
    for (int ks = 0; ks < 4; ++ks) {
        const int ko = ks * 32 + ko0;
        short8 af[4], bA[4], bC[4];
#pragma unroll
        for (int rt = 0; rt < 4; ++rt)
            af[rt] = *(const short8*)(sx + (rt * 16 + m) * 136 + ko);
#pragma unroll
        for (int ct = 0; ct < 4; ++ct) {
            const unsigned short* wp = W1t + (wv * 64 + ct * 16 + m) * 256 + ko;
            bA[ct] = *(const short8*)(wp);         // d in [0,128)  -> A-part
            bC[ct] = *(const short8*)(wp + 128);   // d in [128,256)-> C-part
        }
#pragma unroll
        for (int rt = 0; rt < 4; ++rt)
#pragma unroll
            for (int ct = 0; ct < 4; ++ct) {
                accA[rt * 4 + ct] = __builtin_amdgcn_mfma_f32_16x16x32_bf16(
                    af[rt], bA[ct], accA[rt * 4 + ct], 0, 0, 0);
                accC[rt * 4 + ct] = __builtin_amdgcn_mfma_f32_16x16x32_bf16(
                    af[rt], bC[ct], accC[rt * 4 + ct], 0, 0, 0);
            }
    }

#pragma unroll
    for (int ct = 0; ct < 4; ++ct) {
        const int col = wv * 64 + ct * 16 + m;
        const float bias = b1[col];
#pragma unroll
        for (int rt = 0; rt < 4; ++rt)
#pragma unroll
            for (int j = 0; j < 4; ++j) {
                const int row = rb + rt * 16 + quad * 4 + j;
                float a = accA[rt * 4 + ct][j];
                float d = accC[rt * 4 + ct][j] - a + bias;
                Abf[row * 256 + col] = f2bf(a);
                Dbf[row * 256 + col] = f2bf(d);
            }
    }
}

// ---------------- KNN: two-scan threshold selection, 1 wave = 1 query -------------
// Exact replication of reference fp32 d2 arithmetic; order-independent algorithm.

__device__ __forceinline__ unsigned int d2key(float d2) {
    unsigned int u = __float_as_uint(d2);
    return u ^ (((unsigned int)(((int)u) >> 31)) | 0x80000000u);
}

#define U64MAX 0xFFFFFFFFFFFFFFFFull

__device__ __forceinline__ unsigned long long bitonic64(unsigned long long v, int lane) {
#pragma unroll
    for (int k = 2; k <= 64; k <<= 1) {
#pragma unroll
        for (int j = k >> 1; j > 0; j >>= 1) {
            unsigned long long pv = __shfl_xor(v, j, 64);
            const bool up  = ((lane & k) == 0);
            const bool low = ((lane & j) == 0);
            const unsigned long long mn = (v < pv) ? v : pv;
            const unsigned long long mx = (v < pv) ? pv : v;
            v = (up == low) ? mn : mx;
        }
    }
    return v;
}

#define D2_FROM(px, py)                                                          \
    ({ const float sqj_ = __fadd_rn(__fmul_rn((px), (px)), __fmul_rn((py), (py))); \
       const float t_   = fmaf(yi, (py), __fmul_rn(xi, (px)));                     \
       const float s_   = __fadd_rn(sqi, sqj_);                                    \
       fmaf(-2.0f, t_, s_); })

__global__ __launch_bounds__(256) void knn_kernel(
        const float* __restrict__ points, int* __restrict__ idx_out) {
    __shared__ unsigned long long cand[4][128];
    __shared__ int ccnt[4];

    const int tid  = threadIdx.x;
    const int wv   = tid >> 6;
    const int lane = tid & 63;
    const int q    = (blockIdx.x << 2) + wv;

    const float xi = points[q * 2 + 0];
    const float yi = points[q * 2 + 1];
    const float sqi = __fadd_rn(__fmul_rn(xi, xi), __fmul_rn(yi, yi));

    const float4* p4 = (const float4*)points;   // 2 points per float4

    // ---- scan 1: per-lane minimum over its 128 points (2/iter) ----
    unsigned long long vmin = U64MAX;
#pragma unroll 4
    for (int j = 0; j < 64; ++j) {
        const float4 pp = p4[j * 64 + lane];
        const int i0 = j * 128 + lane * 2;
        {
            const float d2 = D2_FROM(pp.x, pp.y);
            unsigned long long pk = ((unsigned long long)d2key(d2) << 32) | (unsigned int)i0;
            vmin = (pk < vmin) ? pk : vmin;
        }
        {
            const float d2 = D2_FROM(pp.z, pp.w);
            unsigned long long pk = ((unsigned long long)d2key(d2) << 32) | (unsigned int)(i0 + 1);
            vmin = (pk < vmin) ? pk : vmin;
        }
    }

    // ---- 17th-smallest lane-min = safe threshold ----
    unsigned long long v = bitonic64(vmin, lane);
    const unsigned long long T64 = __shfl(v, 16, 64);
    const unsigned int Tkey = (unsigned int)(T64 >> 32);

    if (lane == 0) ccnt[wv] = 0;
    __syncthreads();

    // ---- scan 2: collect candidates with key <= Tkey (expected ~20) ----
#pragma unroll 2
    for (int j = 0; j < 64; ++j) {
        const float4 pp = p4[j * 64 + lane];
        const int i0 = j * 128 + lane * 2;
        {
            const float d2 = D2_FROM(pp.x, pp.y);
            const unsigned int key = d2key(d2);
            if (key <= Tkey) {
                int pos = atomicAdd(&ccnt[wv], 1);
                if (pos < 128)
                    cand[wv][pos] = ((unsigned long long)key << 32) | (unsigned int)i0;
            }
        }
        {
            const float d2 = D2_FROM(pp.z, pp.w);
            const unsigned int key = d2key(d2);
            if (key <= Tkey) {
                int pos = atomicAdd(&ccnt[wv], 1);
                if (pos < 128)
                    cand[wv][pos] = ((unsigned long long)key << 32) | (unsigned int)(i0 + 1);
            }
        }
    }
    __syncthreads();

    const int n = ccnt[wv] < 128 ? ccnt[wv] : 128;
    if (n <= 64) {
        // fast path: full sort of candidates; lane k holds k-th smallest
        unsigned long long v0 = (lane < n) ? cand[wv][lane] : U64MAX;
        v0 = bitonic64(v0, lane);
        if (lane >= 1 && lane <= 16)
            idx_out[q * 16 + lane - 1] = (int)(unsigned int)(v0 & 0xFFFFFFFFull);
    } else {
        // slow path: 17 iterated wave-min extractions
        unsigned long long v0 = (lane < n)      ? cand[wv][lane]      : U64MAX;
        unsigned long long v1 = (lane + 64 < n) ? cand[wv][lane + 64] : U64MAX;
#pragma unroll 1
        for (int pick = 0; pick < 17; ++pick) {
            unsigned long long m = (v0 < v1) ? v0 : v1;
#pragma unroll
            for (int d = 1; d < 64; d <<= 1) {
                unsigned long long pm = __shfl_xor(m, d, 64);
                m = (pm < m) ? pm : m;
            }
            if (pick > 0 && lane == 0)
                idx_out[q * 16 + pick - 1] = (int)(unsigned int)(m & 0xFFFFFFFFull);
            if (v0 == m) v0 = U64MAX;
            else if (v1 == m) v1 = U64MAX;
        }
    }
}

// ---------------- fused gather + gelu + GEMM2 + gelu + mean ----------------
// block = 4 queries (64 rows), 256 threads (4 waves).
// h1[row] = gelu(A[nb] + D[q]); h2 = gelu(h1 @ W2 + b2); mean over K=16.
__global__ __launch_bounds__(256) void mlp_kernel(
        const unsigned short* __restrict__ Abf, const unsigned short* __restrict__ Dbf,
        const unsigned short* __restrict__ W2t, const float* __restrict__ b2,
        const int* __restrict__ idx, float* __restrict__ out) {
    __shared__ unsigned short sh[64 * 264];   // padded stride 264
    const int tid = threadIdx.x;
    const int qb  = blockIdx.x << 2;

    // Phase 0: build h1 = gelu(A[nb] + D[gq]) as bf16 in LDS
    {
        const int r   = ((tid >> 6) << 4) | (tid & 15);   // row 0..63 (= qlocal*16+k)
        const int seg = (tid >> 4) & 3;                   // 64-col segment
        const int gq  = qb + (r >> 4);
        const int nb  = idx[(gq << 4) + (r & 15)];
        const unsigned short* arow = Abf + nb * 256 + seg * 64;
        const unsigned short* drow = Dbf + gq * 256 + seg * 64;
        unsigned short* dst = sh + r * 264 + seg * 64;
#pragma unroll
        for (int u = 0; u < 8; ++u) {
            short8 av = *(const short8*)(arow + u * 8);
            short8 dv = *(const short8*)(drow + u * 8);
            short8 hv;
#pragma unroll
            for (int e = 0; e < 8; ++e) {
                float h = bf2f(av[e]) + bf2f(dv[e]);
                hv[e] = (short)f2bf(gelu_fast(h));
            }
            *(short8*)(dst + u * 8) = hv;
        }
    }
    __syncthreads();

    const int lane = tid & 63, wv = tid >> 6;
    const int m = lane & 15, quad = lane >> 4;
    const int ko0 = quad * 8;

    // Phase 2: h2 = gelu(h1 @ W2 + b2)  (64x128 = 4 row-tiles x 2 col-tiles/wave)
    f32x4 acc2[8];
#pragma unroll
    for (int i = 0; i < 8; ++i) acc2[i] = (f32x4){0.f, 0.f, 0.f, 0.f};
#pragma unroll
    for (int ks = 0; ks < 8; ++ks) {
        const int ko = ks * 32 + ko0;
        short8 af[4], bfr[2];
#pragma unroll
        for (int rt = 0; rt < 4; ++rt)
            af[rt] = *(const short8*)(sh + (rt * 16 + m) * 264 + ko);
#pragma unroll
        for (int ct = 0; ct < 2; ++ct)
            bfr[ct] = *(const short8*)(W2t + (wv * 32 + ct * 16 + m) * 256 + ko);
#pragma unroll
        for (int rt = 0; rt < 4; ++rt)
#pragma unroll
            for (int ct = 0; ct < 2; ++ct)
                acc2[rt * 2 + ct] = __builtin_amdgcn_mfma_f32_16x16x32_bf16(
                    af[rt], bfr[ct], acc2[rt * 2 + ct], 0, 0, 0);
    }

    // Epilogue: bias + gelu, mean over K=16, store f32
#pragma unroll
    for (int ct = 0; ct < 2; ++ct) {
        const int col = wv * 32 + ct * 16 + m;
        const float bias = b2[col];
#pragma unroll
        for (int rt = 0; rt < 4; ++rt) {
            float s = 0.f;
#pragma unroll
            for (int j = 0; j < 4; ++j)
                s += gelu_fast(acc2[rt * 2 + ct][j] + bias);
            s += __shfl_xor(s, 16, 64);
            s += __shfl_xor(s, 32, 64);
            if (quad == 0) out[(qb + rt) * 128 + col] = s * 0.0625f;
        }
    }
}

extern "C" void kernel_launch(void* const* d_in, const int* in_sizes, int n_in,
                              void* d_out, int out_size, void* d_ws, size_t ws_size,
                              hipStream_t stream) {
    const float* x      = (const float*)d_in[0];   // (1,8192,128)
    const float* points = (const float*)d_in[1];   // (1,8192,2)
    const float* W1     = (const float*)d_in[2];   // (256,256)
    const float* b1     = (const float*)d_in[3];   // (256,)
    const float* W2     = (const float*)d_in[4];   // (256,128)
    const float* b2     = (const float*)d_in[5];   // (128,)
    float* out = (float*)d_out;

    char* ws = (char*)d_ws;
    unsigned short* W1t = (unsigned short*)ws;                   // 131072 B
    unsigned short* W2t = (unsigned short*)(ws + 131072);        //  65536 B
    int*            idx = (int*)(ws + 196608);                   // 524288 B
    unsigned short* Abf = (unsigned short*)(ws + 720896);        // 4 MiB
    unsigned short* Dbf = (unsigned short*)(ws + 4915200);       // 4 MiB

    wconv_kernel<<<384, 256, 0, stream>>>(W1, W2, W1t, W2t);
    gemmAD_kernel<<<128, 256, 0, stream>>>(x, W1t, b1, Abf, Dbf);
    knn_kernel<<<2048, 256, 0, stream>>>(points, idx);
    mlp_kernel<<<2048, 256, 0, stream>>>(Abf, Dbf, W2t, b2, idx, out);
}

// Round 5
// 154.895 us; speedup vs baseline: 9.7310x; 1.0192x over previous
//
#include <hip/hip_runtime.h>

typedef __attribute__((ext_vector_type(8))) short short8;
typedef __attribute__((ext_vector_type(4))) float f32x4;

__device__ __forceinline__ unsigned short f2bf(float f) {
    unsigned int u = __float_as_uint(f);
    unsigned int r = u + 0x7fffu + ((u >> 16) & 1u);  // RNE
    return (unsigned short)(r >> 16);
}

__device__ __forceinline__ float bf2f(short s) {
    return __uint_as_float(((unsigned int)(unsigned short)s) << 16);
}

// tanh-form gelu: x * sigmoid(2*sqrt(2/pi)*(x + 0.044715 x^3)); max dev from
// exact erf-gelu ~3e-4 << bf16 noise. exp2/rcp are single HW instructions.
__device__ __forceinline__ float gelu_fast(float v) {
    float x2 = v * v;
    float s  = v * fmaf(-0.102943195f, x2, -2.3022077f);   // -2z*log2(e)
    float e  = __builtin_amdgcn_exp2f(s);
    return v * __builtin_amdgcn_rcpf(1.0f + e);
}

// ---------------- weight convert: f32 row-major -> bf16 transposed ----------------
__global__ __launch_bounds__(256) void wconv_kernel(
        const float* __restrict__ W1, const float* __restrict__ W2,
        unsigned short* __restrict__ W1t, unsigned short* __restrict__ W2t) {
    int g = blockIdx.x * 256 + threadIdx.x;
    if (g < 65536) {                       // W1: (256,256) -> W1t[c][d]
        int d = g >> 8, c = g & 255;
        W1t[c * 256 + d] = f2bf(W1[g]);
    } else if (g < 98304) {                // W2: (256,128) -> W2t[c][d]
        int g2 = g - 65536;
        int d = g2 >> 7, c = g2 & 127;
        W2t[c * 256 + d] = f2bf(W2[g2]);
    }
}

// ---------------- precompute A = x@W1[:128], D = x@W1[128:] - A + b1 (bf16) -------
// 256 blocks: row-block (64 rows) x col-block (128 cols). 4 waves x 32 cols.
// [R5 bisect arm: this is the ONLY change vs the R3-passing source]
__global__ __launch_bounds__(256) void gemmAD_kernel(
        const float* __restrict__ x, const unsigned short* __restrict__ W1t,
        const float* __restrict__ b1,
        unsigned short* __restrict__ Abf, unsigned short* __restrict__ Dbf) {
    __shared__ unsigned short sx[64 * 136];    // 64 rows x 128 bf16, stride 136
    const int tid = threadIdx.x;
    const int rb  = (blockIdx.x >> 1) * 64;
    const int cb  = (blockIdx.x & 1) * 128;

    {   // stage x rows -> bf16 LDS
        const int r   = ((tid >> 6) << 4) | (tid & 15);   // row 0..63
        const int seg = (tid >> 4) & 3;                   // 32-float segment
        const float* xr = x + (rb + r) * 128 + seg * 32;
        unsigned short* dst = sx + r * 136 + seg * 32;
#pragma unroll
        for (int u = 0; u < 8; ++u) {
            float4 a = ((const float4*)xr)[u];
            uint2 w;
            w.x = (unsigned)f2bf(a.x) | ((unsigned)f2bf(a.y) << 16);
            w.y = (unsigned)f2bf(a.z) | ((unsigned)f2bf(a.w) << 16);
            *(uint2*)(dst + u * 4) = w;
        }
    }
    __syncthreads();

    const int lane = tid & 63, wv = tid >> 6;
    const int m = lane & 15, quad = lane >> 4;
    const int ko0 = quad * 8;

    f32x4 accA[8], accC[8];
#pragma unroll
    for (int i = 0; i < 8; ++i) { accA[i] = (f32x4){0,0,0,0}; accC[i] = (f32x4){0,0,0,0}; }

#pragma unroll
    for (int ks = 0; ks < 4; ++ks) {
        const int ko = ks * 32 + ko0;
        short8 af[4], bA[2], bC[2];
#pragma unroll
        for (int rt = 0; rt < 4; ++rt)
            af[rt] = *(const short8*)(sx + (rt * 16 + m) * 136 + ko);
#pragma unroll
        for (int ct = 0; ct < 2; ++ct) {
            const unsigned short* wp = W1t + (cb + wv * 32 + ct * 16 + m) * 256 + ko;
            bA[ct] = *(const short8*)(wp);         // d in [0,128)  -> A-part
            bC[ct] = *(const short8*)(wp + 128);   // d in [128,256)-> C-part
        }
#pragma unroll
        for (int rt = 0; rt < 4; ++rt)
#pragma unroll
            for (int ct = 0; ct < 2; ++ct) {
                accA[rt * 2 + ct] = __builtin_amdgcn_mfma_f32_16x16x32_bf16(
                    af[rt], bA[ct], accA[rt * 2 + ct], 0, 0, 0);
                accC[rt * 2 + ct] = __builtin_amdgcn_mfma_f32_16x16x32_bf16(
                    af[rt], bC[ct], accC[rt * 2 + ct], 0, 0, 0);
            }
    }

#pragma unroll
    for (int ct = 0; ct < 2; ++ct) {
        const int col = cb + wv * 32 + ct * 16 + m;
        const float bias = b1[col];
#pragma unroll
        for (int rt = 0; rt < 4; ++rt)
#pragma unroll
            for (int j = 0; j < 4; ++j) {
                const int row = rb + rt * 16 + quad * 4 + j;
                float a = accA[rt * 2 + ct][j];
                float d = accC[rt * 2 + ct][j] - a + bias;
                Abf[row * 256 + col] = f2bf(a);
                Dbf[row * 256 + col] = f2bf(d);
            }
    }
}

// ---------------- KNN: two-scan threshold selection, 1 wave = 1 query -------------
// [R3-verbatim: u64 lane-min threshold; exact replication of reference fp32 d2]

__device__ __forceinline__ unsigned int d2key(float d2) {
    unsigned int u = __float_as_uint(d2);
    return u ^ (((unsigned int)(((int)u) >> 31)) | 0x80000000u);
}

#define U64MAX 0xFFFFFFFFFFFFFFFFull

__device__ __forceinline__ unsigned long long bitonic64(unsigned long long v, int lane) {
#pragma unroll
    for (int k = 2; k <= 64; k <<= 1) {
#pragma unroll
        for (int j = k >> 1; j > 0; j >>= 1) {
            unsigned long long pv = __shfl_xor(v, j, 64);
            const bool up  = ((lane & k) == 0);
            const bool low = ((lane & j) == 0);
            const unsigned long long mn = (v < pv) ? v : pv;
            const unsigned long long mx = (v < pv) ? pv : v;
            v = (up == low) ? mn : mx;
        }
    }
    return v;
}

#define D2_FROM(px, py)                                                          \
    ({ const float sqj_ = __fadd_rn(__fmul_rn((px), (px)), __fmul_rn((py), (py))); \
       const float t_   = fmaf(yi, (py), __fmul_rn(xi, (px)));                     \
       const float s_   = __fadd_rn(sqi, sqj_);                                    \
       fmaf(-2.0f, t_, s_); })

__global__ __launch_bounds__(256) void knn_kernel(
        const float* __restrict__ points, int* __restrict__ idx_out) {
    __shared__ unsigned long long cand[4][128];
    __shared__ int ccnt[4];

    const int tid  = threadIdx.x;
    const int wv   = tid >> 6;
    const int lane = tid & 63;
    const int q    = (blockIdx.x << 2) + wv;

    const float xi = points[q * 2 + 0];
    const float yi = points[q * 2 + 1];
    const float sqi = __fadd_rn(__fmul_rn(xi, xi), __fmul_rn(yi, yi));

    const float4* p4 = (const float4*)points;   // 2 points per float4

    // ---- scan 1: per-lane minimum over its 128 points (2/iter) ----
    unsigned long long vmin = U64MAX;
#pragma unroll 4
    for (int j = 0; j < 64; ++j) {
        const float4 pp = p4[j * 64 + lane];
        const int i0 = j * 128 + lane * 2;
        {
            const float d2 = D2_FROM(pp.x, pp.y);
            unsigned long long pk = ((unsigned long long)d2key(d2) << 32) | (unsigned int)i0;
            vmin = (pk < vmin) ? pk : vmin;
        }
        {
            const float d2 = D2_FROM(pp.z, pp.w);
            unsigned long long pk = ((unsigned long long)d2key(d2) << 32) | (unsigned int)(i0 + 1);
            vmin = (pk < vmin) ? pk : vmin;
        }
    }

    // ---- 17th-smallest lane-min = safe threshold ----
    unsigned long long v = bitonic64(vmin, lane);
    const unsigned long long T64 = __shfl(v, 16, 64);
    const unsigned int Tkey = (unsigned int)(T64 >> 32);

    if (lane == 0) ccnt[wv] = 0;
    __syncthreads();

    // ---- scan 2: collect candidates with key <= Tkey (expected ~20) ----
#pragma unroll 2
    for (int j = 0; j < 64; ++j) {
        const float4 pp = p4[j * 64 + lane];
        const int i0 = j * 128 + lane * 2;
        {
            const float d2 = D2_FROM(pp.x, pp.y);
            const unsigned int key = d2key(d2);
            if (key <= Tkey) {
                int pos = atomicAdd(&ccnt[wv], 1);
                if (pos < 128)
                    cand[wv][pos] = ((unsigned long long)key << 32) | (unsigned int)i0;
            }
        }
        {
            const float d2 = D2_FROM(pp.z, pp.w);
            const unsigned int key = d2key(d2);
            if (key <= Tkey) {
                int pos = atomicAdd(&ccnt[wv], 1);
                if (pos < 128)
                    cand[wv][pos] = ((unsigned long long)key << 32) | (unsigned int)(i0 + 1);
            }
        }
    }
    __syncthreads();

    const int n = ccnt[wv] < 128 ? ccnt[wv] : 128;
    if (n <= 64) {
        // fast path: full sort of candidates; lane k holds k-th smallest
        unsigned long long v0 = (lane < n) ? cand[wv][lane] : U64MAX;
        v0 = bitonic64(v0, lane);
        if (lane >= 1 && lane <= 16)
            idx_out[q * 16 + lane - 1] = (int)(unsigned int)(v0 & 0xFFFFFFFFull);
    } else {
        // slow path: 17 iterated wave-min extractions
        unsigned long long v0 = (lane < n)      ? cand[wv][lane]      : U64MAX;
        unsigned long long v1 = (lane + 64 < n) ? cand[wv][lane + 64] : U64MAX;
#pragma unroll 1
        for (int pick = 0; pick < 17; ++pick) {
            unsigned long long m = (v0 < v1) ? v0 : v1;
#pragma unroll
            for (int d = 1; d < 64; d <<= 1) {
                unsigned long long pm = __shfl_xor(m, d, 64);
                m = (pm < m) ? pm : m;
            }
            if (pick > 0 && lane == 0)
                idx_out[q * 16 + pick - 1] = (int)(unsigned int)(m & 0xFFFFFFFFull);
            if (v0 == m) v0 = U64MAX;
            else if (v1 == m) v1 = U64MAX;
        }
    }
}

// ---------------- fused gather + gelu + GEMM2 + gelu + mean ----------------
// block = 4 queries (64 rows), 256 threads (4 waves).
// h1[row] = gelu(A[nb] + D[q]); h2 = gelu(h1 @ W2 + b2); mean over K=16.
__global__ __launch_bounds__(256) void mlp_kernel(
        const unsigned short* __restrict__ Abf, const unsigned short* __restrict__ Dbf,
        const unsigned short* __restrict__ W2t, const float* __restrict__ b2,
        const int* __restrict__ idx, float* __restrict__ out) {
    __shared__ unsigned short sh[64 * 264];   // padded stride 264
    const int tid = threadIdx.x;
    const int qb  = blockIdx.x << 2;

    // Phase 0: build h1 = gelu(A[nb] + D[gq]) as bf16 in LDS
    {
        const int r   = ((tid >> 6) << 4) | (tid & 15);   // row 0..63 (= qlocal*16+k)
        const int seg = (tid >> 4) & 3;                   // 64-col segment
        const int gq  = qb + (r >> 4);
        const int nb  = idx[(gq << 4) + (r & 15)];
        const unsigned short* arow = Abf + nb * 256 + seg * 64;
        const unsigned short* drow = Dbf + gq * 256 + seg * 64;
        unsigned short* dst = sh + r * 264 + seg * 64;
#pragma unroll
        for (int u = 0; u < 8; ++u) {
            short8 av = *(const short8*)(arow + u * 8);
            short8 dv = *(const short8*)(drow + u * 8);
            short8 hv;
#pragma unroll
            for (int e = 0; e < 8; ++e) {
                float h = bf2f(av[e]) + bf2f(dv[e]);
                hv[e] = (short)f2bf(gelu_fast(h));
            }
            *(short8*)(dst + u * 8) = hv;
        }
    }
    __syncthreads();

    const int lane = tid & 63, wv = tid >> 6;
    const int m = lane & 15, quad = lane >> 4;
    const int ko0 = quad * 8;

    // Phase 2: h2 = gelu(h1 @ W2 + b2)  (64x128 = 4 row-tiles x 2 col-tiles/wave)
    f32x4 acc2[8];
#pragma unroll
    for (int i = 0; i < 8; ++i) acc2[i] = (f32x4){0.f, 0.f, 0.f, 0.f};
#pragma unroll
    for (int ks = 0; ks < 8; ++ks) {
        const int ko = ks * 32 + ko0;
        short8 af[4], bfr[2];
#pragma unroll
        for (int rt = 0; rt < 4; ++rt)
            af[rt] = *(const short8*)(sh + (rt * 16 + m) * 264 + ko);
#pragma unroll
        for (int ct = 0; ct < 2; ++ct)
            bfr[ct] = *(const short8*)(W2t + (wv * 32 + ct * 16 + m) * 256 + ko);
#pragma unroll
        for (int rt = 0; rt < 4; ++rt)
#pragma unroll
            for (int ct = 0; ct < 2; ++ct)
                acc2[rt * 2 + ct] = __builtin_amdgcn_mfma_f32_16x16x32_bf16(
                    af[rt], bfr[ct], acc2[rt * 2 + ct], 0, 0, 0);
    }

    // Epilogue: bias + gelu, mean over K=16, store f32
#pragma unroll
    for (int ct = 0; ct < 2; ++ct) {
        const int col = wv * 32 + ct * 16 + m;
        const float bias = b2[col];
#pragma unroll
        for (int rt = 0; rt < 4; ++rt) {
            float s = 0.f;
#pragma unroll
            for (int j = 0; j < 4; ++j)
                s += gelu_fast(acc2[rt * 2 + ct][j] + bias);
            s += __shfl_xor(s, 16, 64);
            s += __shfl_xor(s, 32, 64);
            if (quad == 0) out[(qb + rt) * 128 + col] = s * 0.0625f;
        }
    }
}

extern "C" void kernel_launch(void* const* d_in, const int* in_sizes, int n_in,
                              void* d_out, int out_size, void* d_ws, size_t ws_size,
                              hipStream_t stream) {
    const float* x      = (const float*)d_in[0];   // (1,8192,128)
    const float* points = (const float*)d_in[1];   // (1,8192,2)
    const float* W1     = (const float*)d_in[2];   // (256,256)
    const float* b1     = (const float*)d_in[3];   // (256,)
    const float* W2     = (const float*)d_in[4];   // (256,128)
    const float* b2     = (const float*)d_in[5];   // (128,)
    float* out = (float*)d_out;

    char* ws = (char*)d_ws;
    unsigned short* W1t = (unsigned short*)ws;                   // 131072 B
    unsigned short* W2t = (unsigned short*)(ws + 131072);        //  65536 B
    int*            idx = (int*)(ws + 196608);                   // 524288 B
    unsigned short* Abf = (unsigned short*)(ws + 720896);        // 4 MiB
    unsigned short* Dbf = (unsigned short*)(ws + 4915200);       // 4 MiB

    wconv_kernel<<<384, 256, 0, stream>>>(W1, W2, W1t, W2t);
    gemmAD_kernel<<<256, 256, 0, stream>>>(x, W1t, b1, Abf, Dbf);
    knn_kernel<<<2048, 256, 0, stream>>>(points, idx);
    mlp_kernel<<<2048, 256, 0, stream>>>(Abf, Dbf, W2t, b2, idx, out);
}

// Round 7
// 153.308 us; speedup vs baseline: 9.8317x; 1.0104x over previous
//
#include <hip/hip_runtime.h>

typedef __attribute__((ext_vector_type(8))) short short8;
typedef __attribute__((ext_vector_type(4))) float f32x4;

__device__ __forceinline__ unsigned short f2bf(float f) {
    unsigned int u = __float_as_uint(f);
    unsigned int r = u + 0x7fffu + ((u >> 16) & 1u);  // RNE
    return (unsigned short)(r >> 16);
}

__device__ __forceinline__ float bf2f(short s) {
    return __uint_as_float(((unsigned int)(unsigned short)s) << 16);
}

// tanh-form gelu: x * sigmoid(2*sqrt(2/pi)*(x + 0.044715 x^3)); max dev from
// exact erf-gelu ~3e-4 << bf16 noise. exp2/rcp are single HW instructions.
__device__ __forceinline__ float gelu_fast(float v) {
    float x2 = v * v;
    float s  = v * fmaf(-0.102943195f, x2, -2.3022077f);   // -2z*log2(e)
    float e  = __builtin_amdgcn_exp2f(s);
    return v * __builtin_amdgcn_rcpf(1.0f + e);
}

__device__ __forceinline__ unsigned int d2key(float d2) {
    unsigned int u = __float_as_uint(d2);
    return u ^ (((unsigned int)(((int)u) >> 31)) | 0x80000000u);
}

#define U64MAX 0xFFFFFFFFFFFFFFFFull

#define D2_FROM(px, py)                                                          \
    ({ const float sqj_ = __fadd_rn(__fmul_rn((px), (px)), __fmul_rn((py), (py))); \
       const float t_   = fmaf(yi, (py), __fmul_rn(xi, (px)));                     \
       const float s_   = __fadd_rn(sqi, sqj_);                                    \
       fmaf(-2.0f, t_, s_); })

__device__ __forceinline__ unsigned long long bitonic64(unsigned long long v, int lane) {
#pragma unroll
    for (int k = 2; k <= 64; k <<= 1) {
#pragma unroll
        for (int j = k >> 1; j > 0; j >>= 1) {
            unsigned long long pv = __shfl_xor(v, j, 64);
            const bool up  = ((lane & k) == 0);
            const bool low = ((lane & j) == 0);
            const unsigned long long mn = (v < pv) ? v : pv;
            const unsigned long long mx = (v < pv) ? pv : v;
            v = (up == low) ? mn : mx;
        }
    }
    return v;
}

// ---------------- K1: fused wconv (blocks 0..383) + knn scan-1 (blocks 384..2431) ----
// scan-1 is the R5-passing u64 lex-min + bitonic64 path, VERBATIM (the 32-bit
// variants failed on HW twice — R4, R6 — despite on-paper equivalence; the
// threshold path stays 64-bit permanently). Only Tkey is exported via ws.
__global__ __launch_bounds__(256) void prep_kernel(
        const float* __restrict__ points,
        const float* __restrict__ W1, const float* __restrict__ W2,
        unsigned short* __restrict__ W1t, unsigned short* __restrict__ W2t,
        unsigned int* __restrict__ Tq) {
    const int bid = blockIdx.x;
    const int tid = threadIdx.x;

    if (bid < 384) {                       // ---- wconv ----
        int g = bid * 256 + tid;
        if (g < 65536) {                   // W1: (256,256) -> W1t[c][d]
            int d = g >> 8, c = g & 255;
            W1t[c * 256 + d] = f2bf(W1[g]);
        } else if (g < 98304) {            // W2: (256,128) -> W2t[c][d]
            int g2 = g - 65536;
            int d = g2 >> 7, c = g2 & 127;
            W2t[c * 256 + d] = f2bf(W2[g2]);
        }
        return;
    }

    // ---- knn scan-1 [R5-verbatim u64 path] ----
    const int wv   = tid >> 6;
    const int lane = tid & 63;
    const int q    = ((bid - 384) << 2) + wv;

    const float xi = points[q * 2 + 0];
    const float yi = points[q * 2 + 1];
    const float sqi = __fadd_rn(__fmul_rn(xi, xi), __fmul_rn(yi, yi));

    const float4* p4 = (const float4*)points;   // 2 points per float4

    unsigned long long vmin = U64MAX;
#pragma unroll 4
    for (int j = 0; j < 64; ++j) {
        const float4 pp = p4[j * 64 + lane];
        const int i0 = j * 128 + lane * 2;
        {
            const float d2 = D2_FROM(pp.x, pp.y);
            unsigned long long pk = ((unsigned long long)d2key(d2) << 32) | (unsigned int)i0;
            vmin = (pk < vmin) ? pk : vmin;
        }
        {
            const float d2 = D2_FROM(pp.z, pp.w);
            unsigned long long pk = ((unsigned long long)d2key(d2) << 32) | (unsigned int)(i0 + 1);
            vmin = (pk < vmin) ? pk : vmin;
        }
    }

    // ---- 17th-smallest lane-min = safe threshold ----
    unsigned long long v = bitonic64(vmin, lane);
    const unsigned long long T64 = __shfl(v, 16, 64);
    const unsigned int Tkey = (unsigned int)(T64 >> 32);
    if (lane == 0) Tq[q] = Tkey;
}

// ---------------- K2: knn scan-2 + exact lexicographic selection ----------------
// [R5-verbatim scan-2/extraction; Tkey read from ws]
__global__ __launch_bounds__(256) void knn2_kernel(
        const float* __restrict__ points, const unsigned int* __restrict__ Tq,
        int* __restrict__ idx_out) {
    __shared__ unsigned long long cand[4][128];
    __shared__ int ccnt[4];

    const int tid  = threadIdx.x;
    const int wv   = tid >> 6;
    const int lane = tid & 63;
    const int q    = (blockIdx.x << 2) + wv;

    const float xi = points[q * 2 + 0];
    const float yi = points[q * 2 + 1];
    const float sqi = __fadd_rn(__fmul_rn(xi, xi), __fmul_rn(yi, yi));
    const unsigned int Tkey = Tq[q];

    const float4* p4 = (const float4*)points;

    if (lane == 0) ccnt[wv] = 0;
    __syncthreads();

    // ---- scan 2: collect candidates with key <= Tkey (expected ~20) ----
#pragma unroll 2
    for (int j = 0; j < 64; ++j) {
        const float4 pp = p4[j * 64 + lane];
        const int i0 = j * 128 + lane * 2;
        {
            const float d2 = D2_FROM(pp.x, pp.y);
            const unsigned int key = d2key(d2);
            if (key <= Tkey) {
                int pos = atomicAdd(&ccnt[wv], 1);
                if (pos < 128)
                    cand[wv][pos] = ((unsigned long long)key << 32) | (unsigned int)i0;
            }
        }
        {
            const float d2 = D2_FROM(pp.z, pp.w);
            const unsigned int key = d2key(d2);
            if (key <= Tkey) {
                int pos = atomicAdd(&ccnt[wv], 1);
                if (pos < 128)
                    cand[wv][pos] = ((unsigned long long)key << 32) | (unsigned int)(i0 + 1);
            }
        }
    }
    __syncthreads();

    const int n = ccnt[wv] < 128 ? ccnt[wv] : 128;
    if (n <= 64) {
        // fast path: full sort of candidates; lane k holds k-th smallest
        unsigned long long v0 = (lane < n) ? cand[wv][lane] : U64MAX;
        v0 = bitonic64(v0, lane);
        if (lane >= 1 && lane <= 16)
            idx_out[q * 16 + lane - 1] = (int)(unsigned int)(v0 & 0xFFFFFFFFull);
    } else {
        // slow path: 17 iterated wave-min extractions
        unsigned long long v0 = (lane < n)      ? cand[wv][lane]      : U64MAX;
        unsigned long long v1 = (lane + 64 < n) ? cand[wv][lane + 64] : U64MAX;
#pragma unroll 1
        for (int pick = 0; pick < 17; ++pick) {
            unsigned long long m = (v0 < v1) ? v0 : v1;
#pragma unroll
            for (int d = 1; d < 64; d <<= 1) {
                unsigned long long pm = __shfl_xor(m, d, 64);
                m = (pm < m) ? pm : m;
            }
            if (pick > 0 && lane == 0)
                idx_out[q * 16 + pick - 1] = (int)(unsigned int)(m & 0xFFFFFFFFull);
            if (v0 == m) v0 = U64MAX;
            else if (v1 == m) v1 = U64MAX;
        }
    }
}

// ---------------- precompute A = x@W1[:128], D = x@W1[128:] - A + b1 (bf16) -------
// 256 blocks: row-block (64 rows) x col-block (128 cols). [R5-verbatim]
__global__ __launch_bounds__(256) void gemmAD_kernel(
        const float* __restrict__ x, const unsigned short* __restrict__ W1t,
        const float* __restrict__ b1,
        unsigned short* __restrict__ Abf, unsigned short* __restrict__ Dbf) {
    __shared__ unsigned short sx[64 * 136];    // 64 rows x 128 bf16, stride 136
    const int tid = threadIdx.x;
    const int rb  = (blockIdx.x >> 1) * 64;
    const int cb  = (blockIdx.x & 1) * 128;

    {   // stage x rows -> bf16 LDS
        const int r   = ((tid >> 6) << 4) | (tid & 15);   // row 0..63
        const int seg = (tid >> 4) & 3;                   // 32-float segment
        const float* xr = x + (rb + r) * 128 + seg * 32;
        unsigned short* dst = sx + r * 136 + seg * 32;
#pragma unroll
        for (int u = 0; u < 8; ++u) {
            float4 a = ((const float4*)xr)[u];
            uint2 w;
            w.x = (unsigned)f2bf(a.x) | ((unsigned)f2bf(a.y) << 16);
            w.y = (unsigned)f2bf(a.z) | ((unsigned)f2bf(a.w) << 16);
            *(uint2*)(dst + u * 4) = w;
        }
    }
    __syncthreads();

    const int lane = tid & 63, wv = tid >> 6;
    const int m = lane & 15, quad = lane >> 4;
    const int ko0 = quad * 8;

    f32x4 accA[8], accC[8];
#pragma unroll
    for (int i = 0; i < 8; ++i) { accA[i] = (f32x4){0,0,0,0}; accC[i] = (f32x4){0,0,0,0}; }

#pragma unroll
    for (int ks = 0; ks < 4; ++ks) {
        const int ko = ks * 32 + ko0;
        short8 af[4], bA[2], bC[2];
#pragma unroll
        for (int rt = 0; rt < 4; ++rt)
            af[rt] = *(const short8*)(sx + (rt * 16 + m) * 136 + ko);
#pragma unroll
        for (int ct = 0; ct < 2; ++ct) {
            const unsigned short* wp = W1t + (cb + wv * 32 + ct * 16 + m) * 256 + ko;
            bA[ct] = *(const short8*)(wp);         // d in [0,128)  -> A-part
            bC[ct] = *(const short8*)(wp + 128);   // d in [128,256)-> C-part
        }
#pragma unroll
        for (int rt = 0; rt < 4; ++rt)
#pragma unroll
            for (int ct = 0; ct < 2; ++ct) {
                accA[rt * 2 + ct] = __builtin_amdgcn_mfma_f32_16x16x32_bf16(
                    af[rt], bA[ct], accA[rt * 2 + ct], 0, 0, 0);
                accC[rt * 2 + ct] = __builtin_amdgcn_mfma_f32_16x16x32_bf16(
                    af[rt], bC[ct], accC[rt * 2 + ct], 0, 0, 0);
            }
    }

#pragma unroll
    for (int ct = 0; ct < 2; ++ct) {
        const int col = cb + wv * 32 + ct * 16 + m;
        const float bias = b1[col];
#pragma unroll
        for (int rt = 0; rt < 4; ++rt)
#pragma unroll
            for (int j = 0; j < 4; ++j) {
                const int row = rb + rt * 16 + quad * 4 + j;
                float a = accA[rt * 2 + ct][j];
                float d = accC[rt * 2 + ct][j] - a + bias;
                Abf[row * 256 + col] = f2bf(a);
                Dbf[row * 256 + col] = f2bf(d);
            }
    }
}

// ---------------- fused gather + gelu + GEMM2 + gelu + mean [R5-verbatim] ---------
__global__ __launch_bounds__(256) void mlp_kernel(
        const unsigned short* __restrict__ Abf, const unsigned short* __restrict__ Dbf,
        const unsigned short* __restrict__ W2t, const float* __restrict__ b2,
        const int* __restrict__ idx, float* __restrict__ out) {
    __shared__ unsigned short sh[64 * 264];   // padded stride 264
    const int tid = threadIdx.x;
    const int qb  = blockIdx.x << 2;

    // Phase 0: build h1 = gelu(A[nb] + D[gq]) as bf16 in LDS
    {
        const int r   = ((tid >> 6) << 4) | (tid & 15);   // row 0..63 (= qlocal*16+k)
        const int seg = (tid >> 4) & 3;                   // 64-col segment
        const int gq  = qb + (r >> 4);
        const int nb  = idx[(gq << 4) + (r & 15)];
        const unsigned short* arow = Abf + nb * 256 + seg * 64;
        const unsigned short* drow = Dbf + gq * 256 + seg * 64;
        unsigned short* dst = sh + r * 264 + seg * 64;
#pragma unroll
        for (int u = 0; u < 8; ++u) {
            short8 av = *(const short8*)(arow + u * 8);
            short8 dv = *(const short8*)(drow + u * 8);
            short8 hv;
#pragma unroll
            for (int e = 0; e < 8; ++e) {
                float h = bf2f(av[e]) + bf2f(dv[e]);
                hv[e] = (short)f2bf(gelu_fast(h));
            }
            *(short8*)(dst + u * 8) = hv;
        }
    }
    __syncthreads();

    const int lane = tid & 63, wv = tid >> 6;
    const int m = lane & 15, quad = lane >> 4;
    const int ko0 = quad * 8;

    // Phase 2: h2 = gelu(h1 @ W2 + b2)  (64x128 = 4 row-tiles x 2 col-tiles/wave)
    f32x4 acc2[8];
#pragma unroll
    for (int i = 0; i < 8; ++i) acc2[i] = (f32x4){0.f, 0.f, 0.f, 0.f};
#pragma unroll
    for (int ks = 0; ks < 8; ++ks) {
        const int ko = ks * 32 + ko0;
        short8 af[4], bfr[2];
#pragma unroll
        for (int rt = 0; rt < 4; ++rt)
            af[rt] = *(const short8*)(sh + (rt * 16 + m) * 264 + ko);
#pragma unroll
        for (int ct = 0; ct < 2; ++ct)
            bfr[ct] = *(const short8*)(W2t + (wv * 32 + ct * 16 + m) * 256 + ko);
#pragma unroll
        for (int rt = 0; rt < 4; ++rt)
#pragma unroll
            for (int ct = 0; ct < 2; ++ct)
                acc2[rt * 2 + ct] = __builtin_amdgcn_mfma_f32_16x16x32_bf16(
                    af[rt], bfr[ct], acc2[rt * 2 + ct], 0, 0, 0);
    }

    // Epilogue: bias + gelu, mean over K=16, store f32
#pragma unroll
    for (int ct = 0; ct < 2; ++ct) {
        const int col = wv * 32 + ct * 16 + m;
        const float bias = b2[col];
#pragma unroll
        for (int rt = 0; rt < 4; ++rt) {
            float s = 0.f;
#pragma unroll
            for (int j = 0; j < 4; ++j)
                s += gelu_fast(acc2[rt * 2 + ct][j] + bias);
            s += __shfl_xor(s, 16, 64);
            s += __shfl_xor(s, 32, 64);
            if (quad == 0) out[(qb + rt) * 128 + col] = s * 0.0625f;
        }
    }
}

extern "C" void kernel_launch(void* const* d_in, const int* in_sizes, int n_in,
                              void* d_out, int out_size, void* d_ws, size_t ws_size,
                              hipStream_t stream) {
    const float* x      = (const float*)d_in[0];   // (1,8192,128)
    const float* points = (const float*)d_in[1];   // (1,8192,2)
    const float* W1     = (const float*)d_in[2];   // (256,256)
    const float* b1     = (const float*)d_in[3];   // (256,)
    const float* W2     = (const float*)d_in[4];   // (256,128)
    const float* b2     = (const float*)d_in[5];   // (128,)
    float* out = (float*)d_out;

    // ws layout = R5-exact footprint (9109504 B). Tq overlaps Abf's head:
    // prep writes Tq, knn2 consumes it, THEN gemmAD overwrites the region as Abf.
    char* ws = (char*)d_ws;
    unsigned short* W1t = (unsigned short*)ws;                   // 131072 B
    unsigned short* W2t = (unsigned short*)(ws + 131072);        //  65536 B
    int*            idx = (int*)(ws + 196608);                   // 524288 B
    unsigned int*   Tq  = (unsigned int*)(ws + 720896);          //  32768 B (dead before Abf written)
    unsigned short* Abf = (unsigned short*)(ws + 720896);        // 4 MiB
    unsigned short* Dbf = (unsigned short*)(ws + 4915200);       // 4 MiB

    prep_kernel<<<2432, 256, 0, stream>>>(points, W1, W2, W1t, W2t, Tq);
    knn2_kernel<<<2048, 256, 0, stream>>>(points, Tq, idx);
    gemmAD_kernel<<<256, 256, 0, stream>>>(x, W1t, b1, Abf, Dbf);
    mlp_kernel<<<2048, 256, 0, stream>>>(Abf, Dbf, W2t, b2, idx, out);
}

// Round 9
// 152.941 us; speedup vs baseline: 9.8553x; 1.0024x over previous
//
#include <hip/hip_runtime.h>

typedef __attribute__((ext_vector_type(8))) short short8;
typedef __attribute__((ext_vector_type(4))) float f32x4;

__device__ __forceinline__ unsigned short f2bf(float f) {
    unsigned int u = __float_as_uint(f);
    unsigned int r = u + 0x7fffu + ((u >> 16) & 1u);  // RNE
    return (unsigned short)(r >> 16);
}

__device__ __forceinline__ float bf2f(short s) {
    return __uint_as_float(((unsigned int)(unsigned short)s) << 16);
}

// tanh-form gelu: x * sigmoid(2*sqrt(2/pi)*(x + 0.044715 x^3))
__device__ __forceinline__ float gelu_fast(float v) {
    float x2 = v * v;
    float s  = v * fmaf(-0.102943195f, x2, -2.3022077f);   // -2z*log2(e)
    float e  = __builtin_amdgcn_exp2f(s);
    return v * __builtin_amdgcn_rcpf(1.0f + e);
}

__device__ __forceinline__ unsigned int d2key(float d2) {
    unsigned int u = __float_as_uint(d2);
    return u ^ (((unsigned int)(((int)u) >> 31)) | 0x80000000u);
}

#define U64MAX 0xFFFFFFFFFFFFFFFFull

// FROZEN (R5/R7-passing byte-form). 32-bit and packed variants failed on HW
// three times (R4, R6, R8) despite on-paper equivalence. Do not touch.
#define D2_FROM(px, py)                                                          \
    ({ const float sqj_ = __fadd_rn(__fmul_rn((px), (px)), __fmul_rn((py), (py))); \
       const float t_   = fmaf(yi, (py), __fmul_rn(xi, (px)));                     \
       const float s_   = __fadd_rn(sqi, sqj_);                                    \
       fmaf(-2.0f, t_, s_); })

__device__ __forceinline__ unsigned long long bitonic64(unsigned long long v, int lane) {
#pragma unroll
    for (int k = 2; k <= 64; k <<= 1) {
#pragma unroll
        for (int j = k >> 1; j > 0; j >>= 1) {
            unsigned long long pv = __shfl_xor(v, j, 64);
            const bool up  = ((lane & k) == 0);
            const bool low = ((lane & j) == 0);
            const unsigned long long mn = (v < pv) ? v : pv;
            const unsigned long long mx = (v < pv) ? pv : v;
            v = (up == low) ? mn : mx;
        }
    }
    return v;
}

// ---------------- K1: wconv (blocks 0..383) + monolithic knn (blocks 384..2431) ---
// wconv-branch pattern proven in R7's prep_kernel; knn body is R5's twice-passing
// monolithic scan-1 + scan-2 + extraction, VERBATIM (Tkey stays in-register).
__global__ __launch_bounds__(256) void knn_kernel(
        const float* __restrict__ points,
        const float* __restrict__ W1, const float* __restrict__ W2,
        unsigned short* __restrict__ W1t, unsigned short* __restrict__ W2t,
        int* __restrict__ idx_out) {
    __shared__ unsigned long long cand[4][128];
    __shared__ int ccnt[4];

    const int bid = blockIdx.x;
    const int tid = threadIdx.x;

    if (bid < 384) {                       // ---- wconv ----
        int g = bid * 256 + tid;
        if (g < 65536) {                   // W1: (256,256) -> W1t[c][d]
            int d = g >> 8, c = g & 255;
            W1t[c * 256 + d] = f2bf(W1[g]);
        } else if (g < 98304) {            // W2: (256,128) -> W2t[c][d]
            int g2 = g - 65536;
            int d = g2 >> 7, c = g2 & 127;
            W2t[c * 256 + d] = f2bf(W2[g2]);
        }
        return;
    }

    // ---- knn [R5-verbatim monolithic body] ----
    const int wv   = tid >> 6;
    const int lane = tid & 63;
    const int q    = ((bid - 384) << 2) + wv;

    const float xi = points[q * 2 + 0];
    const float yi = points[q * 2 + 1];
    const float sqi = __fadd_rn(__fmul_rn(xi, xi), __fmul_rn(yi, yi));

    const float4* p4 = (const float4*)points;   // 2 points per float4

    // ---- scan 1: per-lane minimum over its 128 points (2/iter) ----
    unsigned long long vmin = U64MAX;
#pragma unroll 4
    for (int j = 0; j < 64; ++j) {
        const float4 pp = p4[j * 64 + lane];
        const int i0 = j * 128 + lane * 2;
        {
            const float d2 = D2_FROM(pp.x, pp.y);
            unsigned long long pk = ((unsigned long long)d2key(d2) << 32) | (unsigned int)i0;
            vmin = (pk < vmin) ? pk : vmin;
        }
        {
            const float d2 = D2_FROM(pp.z, pp.w);
            unsigned long long pk = ((unsigned long long)d2key(d2) << 32) | (unsigned int)(i0 + 1);
            vmin = (pk < vmin) ? pk : vmin;
        }
    }

    // ---- 17th-smallest lane-min = safe threshold ----
    unsigned long long v = bitonic64(vmin, lane);
    const unsigned long long T64 = __shfl(v, 16, 64);
    const unsigned int Tkey = (unsigned int)(T64 >> 32);

    if (lane == 0) ccnt[wv] = 0;
    __syncthreads();

    // ---- scan 2: collect candidates with key <= Tkey (expected ~20) ----
#pragma unroll 2
    for (int j = 0; j < 64; ++j) {
        const float4 pp = p4[j * 64 + lane];
        const int i0 = j * 128 + lane * 2;
        {
            const float d2 = D2_FROM(pp.x, pp.y);
            const unsigned int key = d2key(d2);
            if (key <= Tkey) {
                int pos = atomicAdd(&ccnt[wv], 1);
                if (pos < 128)
                    cand[wv][pos] = ((unsigned long long)key << 32) | (unsigned int)i0;
            }
        }
        {
            const float d2 = D2_FROM(pp.z, pp.w);
            const unsigned int key = d2key(d2);
            if (key <= Tkey) {
                int pos = atomicAdd(&ccnt[wv], 1);
                if (pos < 128)
                    cand[wv][pos] = ((unsigned long long)key << 32) | (unsigned int)(i0 + 1);
            }
        }
    }
    __syncthreads();

    const int n = ccnt[wv] < 128 ? ccnt[wv] : 128;
    if (n <= 64) {
        // fast path: full sort of candidates; lane k holds k-th smallest
        unsigned long long v0 = (lane < n) ? cand[wv][lane] : U64MAX;
        v0 = bitonic64(v0, lane);
        if (lane >= 1 && lane <= 16)
            idx_out[q * 16 + lane - 1] = (int)(unsigned int)(v0 & 0xFFFFFFFFull);
    } else {
        // slow path: 17 iterated wave-min extractions
        unsigned long long v0 = (lane < n)      ? cand[wv][lane]      : U64MAX;
        unsigned long long v1 = (lane + 64 < n) ? cand[wv][lane + 64] : U64MAX;
#pragma unroll 1
        for (int pick = 0; pick < 17; ++pick) {
            unsigned long long m = (v0 < v1) ? v0 : v1;
#pragma unroll
            for (int d = 1; d < 64; d <<= 1) {
                unsigned long long pm = __shfl_xor(m, d, 64);
                m = (pm < m) ? pm : m;
            }
            if (pick > 0 && lane == 0)
                idx_out[q * 16 + pick - 1] = (int)(unsigned int)(m & 0xFFFFFFFFull);
            if (v0 == m) v0 = U64MAX;
            else if (v1 == m) v1 = U64MAX;
        }
    }
}

// ---------------- K2: A = x@W1[:128], D = x@W1[128:] - A + b1 (bf16) [R7-verbatim]
__global__ __launch_bounds__(256) void gemmAD_kernel(
        const float* __restrict__ x, const unsigned short* __restrict__ W1t,
        const float* __restrict__ b1,
        unsigned short* __restrict__ Abf, unsigned short* __restrict__ Dbf) {
    __shared__ unsigned short sx[64 * 136];    // 64 rows x 128 bf16, stride 136
    const int tid = threadIdx.x;
    const int rb  = (blockIdx.x >> 1) * 64;
    const int cb  = (blockIdx.x & 1) * 128;

    {   // stage x rows -> bf16 LDS
        const int r   = ((tid >> 6) << 4) | (tid & 15);   // row 0..63
        const int seg = (tid >> 4) & 3;                   // 32-float segment
        const float* xr = x + (rb + r) * 128 + seg * 32;
        unsigned short* dst = sx + r * 136 + seg * 32;
#pragma unroll
        for (int u = 0; u < 8; ++u) {
            float4 a = ((const float4*)xr)[u];
            uint2 w;
            w.x = (unsigned)f2bf(a.x) | ((unsigned)f2bf(a.y) << 16);
            w.y = (unsigned)f2bf(a.z) | ((unsigned)f2bf(a.w) << 16);
            *(uint2*)(dst + u * 4) = w;
        }
    }
    __syncthreads();

    const int lane = tid & 63, wv = tid >> 6;
    const int m = lane & 15, quad = lane >> 4;
    const int ko0 = quad * 8;

    f32x4 accA[8], accC[8];
#pragma unroll
    for (int i = 0; i < 8; ++i) { accA[i] = (f32x4){0,0,0,0}; accC[i] = (f32x4){0,0,0,0}; }

#pragma unroll
    for (int ks = 0; ks < 4; ++ks) {
        const int ko = ks * 32 + ko0;
        short8 af[4], bA[2], bC[2];
#pragma unroll
        for (int rt = 0; rt < 4; ++rt)
            af[rt] = *(const short8*)(sx + (rt * 16 + m) * 136 + ko);
#pragma unroll
        for (int ct = 0; ct < 2; ++ct) {
            const unsigned short* wp = W1t + (cb + wv * 32 + ct * 16 + m) * 256 + ko;
            bA[ct] = *(const short8*)(wp);         // d in [0,128)  -> A-part
            bC[ct] = *(const short8*)(wp + 128);   // d in [128,256)-> C-part
        }
#pragma unroll
        for (int rt = 0; rt < 4; ++rt)
#pragma unroll
            for (int ct = 0; ct < 2; ++ct) {
                accA[rt * 2 + ct] = __builtin_amdgcn_mfma_f32_16x16x32_bf16(
                    af[rt], bA[ct], accA[rt * 2 + ct], 0, 0, 0);
                accC[rt * 2 + ct] = __builtin_amdgcn_mfma_f32_16x16x32_bf16(
                    af[rt], bC[ct], accC[rt * 2 + ct], 0, 0, 0);
            }
    }

#pragma unroll
    for (int ct = 0; ct < 2; ++ct) {
        const int col = cb + wv * 32 + ct * 16 + m;
        const float bias = b1[col];
#pragma unroll
        for (int rt = 0; rt < 4; ++rt)
#pragma unroll
            for (int j = 0; j < 4; ++j) {
                const int row = rb + rt * 16 + quad * 4 + j;
                float a = accA[rt * 2 + ct][j];
                float d = accC[rt * 2 + ct][j] - a + bias;
                Abf[row * 256 + col] = f2bf(a);
                Dbf[row * 256 + col] = f2bf(d);
            }
    }
}

// ---------------- K3: fused gather + gelu + GEMM2 + gelu + mean [R7-verbatim] -----
__global__ __launch_bounds__(256) void mlp_kernel(
        const unsigned short* __restrict__ Abf, const unsigned short* __restrict__ Dbf,
        const unsigned short* __restrict__ W2t, const float* __restrict__ b2,
        const int* __restrict__ idx, float* __restrict__ out) {
    __shared__ unsigned short sh[64 * 264];   // padded stride 264
    const int tid = threadIdx.x;
    const int qb  = blockIdx.x << 2;

    // Phase 0: build h1 = gelu(A[nb] + D[gq]) as bf16 in LDS
    {
        const int r   = ((tid >> 6) << 4) | (tid & 15);   // row 0..63 (= qlocal*16+k)
        const int seg = (tid >> 4) & 3;                   // 64-col segment
        const int gq  = qb + (r >> 4);
        const int nb  = idx[(gq << 4) + (r & 15)];
        const unsigned short* arow = Abf + nb * 256 + seg * 64;
        const unsigned short* drow = Dbf + gq * 256 + seg * 64;
        unsigned short* dst = sh + r * 264 + seg * 64;
#pragma unroll
        for (int u = 0; u < 8; ++u) {
            short8 av = *(const short8*)(arow + u * 8);
            short8 dv = *(const short8*)(drow + u * 8);
            short8 hv;
#pragma unroll
            for (int e = 0; e < 8; ++e) {
                float h = bf2f(av[e]) + bf2f(dv[e]);
                hv[e] = (short)f2bf(gelu_fast(h));
            }
            *(short8*)(dst + u * 8) = hv;
        }
    }
    __syncthreads();

    const int lane = tid & 63, wv = tid >> 6;
    const int m = lane & 15, quad = lane >> 4;
    const int ko0 = quad * 8;

    // Phase 2: h2 = gelu(h1 @ W2 + b2)  (64x128 = 4 row-tiles x 2 col-tiles/wave)
    f32x4 acc2[8];
#pragma unroll
    for (int i = 0; i < 8; ++i) acc2[i] = (f32x4){0.f, 0.f, 0.f, 0.f};
#pragma unroll
    for (int ks = 0; ks < 8; ++ks) {
        const int ko = ks * 32 + ko0;
        short8 af[4], bfr[2];
#pragma unroll
        for (int rt = 0; rt < 4; ++rt)
            af[rt] = *(const short8*)(sh + (rt * 16 + m) * 264 + ko);
#pragma unroll
        for (int ct = 0; ct < 2; ++ct)
            bfr[ct] = *(const short8*)(W2t + (wv * 32 + ct * 16 + m) * 256 + ko);
#pragma unroll
        for (int rt = 0; rt < 4; ++rt)
#pragma unroll
            for (int ct = 0; ct < 2; ++ct)
                acc2[rt * 2 + ct] = __builtin_amdgcn_mfma_f32_16x16x32_bf16(
                    af[rt], bfr[ct], acc2[rt * 2 + ct], 0, 0, 0);
    }

    // Epilogue: bias + gelu, mean over K=16, store f32
#pragma unroll
    for (int ct = 0; ct < 2; ++ct) {
        const int col = wv * 32 + ct * 16 + m;
        const float bias = b2[col];
#pragma unroll
        for (int rt = 0; rt < 4; ++rt) {
            float s = 0.f;
#pragma unroll
            for (int j = 0; j < 4; ++j)
                s += gelu_fast(acc2[rt * 2 + ct][j] + bias);
            s += __shfl_xor(s, 16, 64);
            s += __shfl_xor(s, 32, 64);
            if (quad == 0) out[(qb + rt) * 128 + col] = s * 0.0625f;
        }
    }
}

extern "C" void kernel_launch(void* const* d_in, const int* in_sizes, int n_in,
                              void* d_out, int out_size, void* d_ws, size_t ws_size,
                              hipStream_t stream) {
    const float* x      = (const float*)d_in[0];   // (1,8192,128)
    const float* points = (const float*)d_in[1];   // (1,8192,2)
    const float* W1     = (const float*)d_in[2];   // (256,256)
    const float* b1     = (const float*)d_in[3];   // (256,)
    const float* W2     = (const float*)d_in[4];   // (256,128)
    const float* b2     = (const float*)d_in[5];   // (128,)
    float* out = (float*)d_out;

    // ws layout = R5-exact (no Tq: threshold stays in-register in K1)
    char* ws = (char*)d_ws;
    unsigned short* W1t = (unsigned short*)ws;                   // 131072 B
    unsigned short* W2t = (unsigned short*)(ws + 131072);        //  65536 B
    int*            idx = (int*)(ws + 196608);                   // 524288 B
    unsigned short* Abf = (unsigned short*)(ws + 720896);        // 4 MiB
    unsigned short* Dbf = (unsigned short*)(ws + 4915200);       // 4 MiB

    knn_kernel<<<2432, 256, 0, stream>>>(points, W1, W2, W1t, W2t, idx);
    gemmAD_kernel<<<256, 256, 0, stream>>>(x, W1t, b1, Abf, Dbf);
    mlp_kernel<<<2048, 256, 0, stream>>>(Abf, Dbf, W2t, b2, idx, out);
}

// Round 10
// 152.595 us; speedup vs baseline: 9.8776x; 1.0023x over previous
//
#include <hip/hip_runtime.h>

typedef __attribute__((ext_vector_type(8))) short short8;
typedef __attribute__((ext_vector_type(4))) float f32x4;

__device__ __forceinline__ unsigned short f2bf(float f) {
    unsigned int u = __float_as_uint(f);
    unsigned int r = u + 0x7fffu + ((u >> 16) & 1u);  // RNE
    return (unsigned short)(r >> 16);
}

__device__ __forceinline__ float bf2f(short s) {
    return __uint_as_float(((unsigned int)(unsigned short)s) << 16);
}

// tanh-form gelu: x * sigmoid(2*sqrt(2/pi)*(x + 0.044715 x^3))
__device__ __forceinline__ float gelu_fast(float v) {
    float x2 = v * v;
    float s  = v * fmaf(-0.102943195f, x2, -2.3022077f);   // -2z*log2(e)
    float e  = __builtin_amdgcn_exp2f(s);
    return v * __builtin_amdgcn_rcpf(1.0f + e);
}

__device__ __forceinline__ unsigned int d2key(float d2) {
    unsigned int u = __float_as_uint(d2);
    return u ^ (((unsigned int)(((int)u) >> 31)) | 0x80000000u);
}

#define U64MAX 0xFFFFFFFFFFFFFFFFull

// FROZEN (R5/R7/R9-passing byte-form). 32-bit and packed variants failed on HW
// three times (R4, R6, R8) despite on-paper equivalence. Do not touch.
#define D2_FROM(px, py)                                                          \
    ({ const float sqj_ = __fadd_rn(__fmul_rn((px), (px)), __fmul_rn((py), (py))); \
       const float t_   = fmaf(yi, (py), __fmul_rn(xi, (px)));                     \
       const float s_   = __fadd_rn(sqi, sqj_);                                    \
       fmaf(-2.0f, t_, s_); })

__device__ __forceinline__ unsigned long long bitonic64(unsigned long long v, int lane) {
#pragma unroll
    for (int k = 2; k <= 64; k <<= 1) {
#pragma unroll
        for (int j = k >> 1; j > 0; j >>= 1) {
            unsigned long long pv = __shfl_xor(v, j, 64);
            const bool up  = ((lane & k) == 0);
            const bool low = ((lane & j) == 0);
            const unsigned long long mn = (v < pv) ? v : pv;
            const unsigned long long mx = (v < pv) ? pv : v;
            v = (up == low) ? mn : mx;
        }
    }
    return v;
}

// ---------------- K1: wconv (blocks 0..383) + monolithic knn (blocks 384..2431) ---
// Per-point instruction sequence is R9-verbatim; only unroll factors raised
// (bit-safe: u64 min-reduction is exact-integer associative; candidate
// insertion order is already nondeterministic with order-independent exact
// extraction).
__global__ __launch_bounds__(256) void knn_kernel(
        const float* __restrict__ points,
        const float* __restrict__ W1, const float* __restrict__ W2,
        unsigned short* __restrict__ W1t, unsigned short* __restrict__ W2t,
        int* __restrict__ idx_out) {
    __shared__ unsigned long long cand[4][128];
    __shared__ int ccnt[4];

    const int bid = blockIdx.x;
    const int tid = threadIdx.x;

    if (bid < 384) {                       // ---- wconv ----
        int g = bid * 256 + tid;
        if (g < 65536) {                   // W1: (256,256) -> W1t[c][d]
            int d = g >> 8, c = g & 255;
            W1t[c * 256 + d] = f2bf(W1[g]);
        } else if (g < 98304) {            // W2: (256,128) -> W2t[c][d]
            int g2 = g - 65536;
            int d = g2 >> 7, c = g2 & 127;
            W2t[c * 256 + d] = f2bf(W2[g2]);
        }
        return;
    }

    // ---- knn ----
    const int wv   = tid >> 6;
    const int lane = tid & 63;
    const int q    = ((bid - 384) << 2) + wv;

    const float xi = points[q * 2 + 0];
    const float yi = points[q * 2 + 1];
    const float sqi = __fadd_rn(__fmul_rn(xi, xi), __fmul_rn(yi, yi));

    const float4* p4 = (const float4*)points;   // 2 points per float4

    // ---- scan 1: per-lane minimum over its 128 points (2/iter) ----
    unsigned long long vmin = U64MAX;
#pragma unroll 8
    for (int j = 0; j < 64; ++j) {
        const float4 pp = p4[j * 64 + lane];
        const int i0 = j * 128 + lane * 2;
        {
            const float d2 = D2_FROM(pp.x, pp.y);
            unsigned long long pk = ((unsigned long long)d2key(d2) << 32) | (unsigned int)i0;
            vmin = (pk < vmin) ? pk : vmin;
        }
        {
            const float d2 = D2_FROM(pp.z, pp.w);
            unsigned long long pk = ((unsigned long long)d2key(d2) << 32) | (unsigned int)(i0 + 1);
            vmin = (pk < vmin) ? pk : vmin;
        }
    }

    // ---- 17th-smallest lane-min = safe threshold ----
    unsigned long long v = bitonic64(vmin, lane);
    const unsigned long long T64 = __shfl(v, 16, 64);
    const unsigned int Tkey = (unsigned int)(T64 >> 32);

    unsigned long long* candw = cand[wv];
    int* ccntw = &ccnt[wv];
    if (lane == 0) *ccntw = 0;
    __syncthreads();

    // ---- scan 2: collect candidates with key <= Tkey (expected ~20) ----
#pragma unroll 4
    for (int j = 0; j < 64; ++j) {
        const float4 pp = p4[j * 64 + lane];
        const int i0 = j * 128 + lane * 2;
        {
            const float d2 = D2_FROM(pp.x, pp.y);
            const unsigned int key = d2key(d2);
            if (key <= Tkey) {
                int pos = atomicAdd(ccntw, 1);
                if (pos < 128)
                    candw[pos] = ((unsigned long long)key << 32) | (unsigned int)i0;
            }
        }
        {
            const float d2 = D2_FROM(pp.z, pp.w);
            const unsigned int key = d2key(d2);
            if (key <= Tkey) {
                int pos = atomicAdd(ccntw, 1);
                if (pos < 128)
                    candw[pos] = ((unsigned long long)key << 32) | (unsigned int)(i0 + 1);
            }
        }
    }
    __syncthreads();

    const int n = *ccntw < 128 ? *ccntw : 128;
    if (n <= 64) {
        // fast path: full sort of candidates; lane k holds k-th smallest
        unsigned long long v0 = (lane < n) ? candw[lane] : U64MAX;
        v0 = bitonic64(v0, lane);
        if (lane >= 1 && lane <= 16)
            idx_out[q * 16 + lane - 1] = (int)(unsigned int)(v0 & 0xFFFFFFFFull);
    } else {
        // slow path: 17 iterated wave-min extractions
        unsigned long long v0 = (lane < n)      ? candw[lane]      : U64MAX;
        unsigned long long v1 = (lane + 64 < n) ? candw[lane + 64] : U64MAX;
#pragma unroll 1
        for (int pick = 0; pick < 17; ++pick) {
            unsigned long long m = (v0 < v1) ? v0 : v1;
#pragma unroll
            for (int d = 1; d < 64; d <<= 1) {
                unsigned long long pm = __shfl_xor(m, d, 64);
                m = (pm < m) ? pm : m;
            }
            if (pick > 0 && lane == 0)
                idx_out[q * 16 + pick - 1] = (int)(unsigned int)(m & 0xFFFFFFFFull);
            if (v0 == m) v0 = U64MAX;
            else if (v1 == m) v1 = U64MAX;
        }
    }
}

// ---------------- K2: A = x@W1[:128], D = x@W1[128:] - A + b1 (bf16) [R9-verbatim]
__global__ __launch_bounds__(256) void gemmAD_kernel(
        const float* __restrict__ x, const unsigned short* __restrict__ W1t,
        const float* __restrict__ b1,
        unsigned short* __restrict__ Abf, unsigned short* __restrict__ Dbf) {
    __shared__ unsigned short sx[64 * 136];    // 64 rows x 128 bf16, stride 136
    const int tid = threadIdx.x;
    const int rb  = (blockIdx.x >> 1) * 64;
    const int cb  = (blockIdx.x & 1) * 128;

    {   // stage x rows -> bf16 LDS
        const int r   = ((tid >> 6) << 4) | (tid & 15);   // row 0..63
        const int seg = (tid >> 4) & 3;                   // 32-float segment
        const float* xr = x + (rb + r) * 128 + seg * 32;
        unsigned short* dst = sx + r * 136 + seg * 32;
#pragma unroll
        for (int u = 0; u < 8; ++u) {
            float4 a = ((const float4*)xr)[u];
            uint2 w;
            w.x = (unsigned)f2bf(a.x) | ((unsigned)f2bf(a.y) << 16);
            w.y = (unsigned)f2bf(a.z) | ((unsigned)f2bf(a.w) << 16);
            *(uint2*)(dst + u * 4) = w;
        }
    }
    __syncthreads();

    const int lane = tid & 63, wv = tid >> 6;
    const int m = lane & 15, quad = lane >> 4;
    const int ko0 = quad * 8;

    f32x4 accA[8], accC[8];
#pragma unroll
    for (int i = 0; i < 8; ++i) { accA[i] = (f32x4){0,0,0,0}; accC[i] = (f32x4){0,0,0,0}; }

#pragma unroll
    for (int ks = 0; ks < 4; ++ks) {
        const int ko = ks * 32 + ko0;
        short8 af[4], bA[2], bC[2];
#pragma unroll
        for (int rt = 0; rt < 4; ++rt)
            af[rt] = *(const short8*)(sx + (rt * 16 + m) * 136 + ko);
#pragma unroll
        for (int ct = 0; ct < 2; ++ct) {
            const unsigned short* wp = W1t + (cb + wv * 32 + ct * 16 + m) * 256 + ko;
            bA[ct] = *(const short8*)(wp);         // d in [0,128)  -> A-part
            bC[ct] = *(const short8*)(wp + 128);   // d in [128,256)-> C-part
        }
#pragma unroll
        for (int rt = 0; rt < 4; ++rt)
#pragma unroll
            for (int ct = 0; ct < 2; ++ct) {
                accA[rt * 2 + ct] = __builtin_amdgcn_mfma_f32_16x16x32_bf16(
                    af[rt], bA[ct], accA[rt * 2 + ct], 0, 0, 0);
                accC[rt * 2 + ct] = __builtin_amdgcn_mfma_f32_16x16x32_bf16(
                    af[rt], bC[ct], accC[rt * 2 + ct], 0, 0, 0);
            }
    }

#pragma unroll
    for (int ct = 0; ct < 2; ++ct) {
        const int col = cb + wv * 32 + ct * 16 + m;
        const float bias = b1[col];
#pragma unroll
        for (int rt = 0; rt < 4; ++rt)
#pragma unroll
            for (int j = 0; j < 4; ++j) {
                const int row = rb + rt * 16 + quad * 4 + j;
                float a = accA[rt * 2 + ct][j];
                float d = accC[rt * 2 + ct][j] - a + bias;
                Abf[row * 256 + col] = f2bf(a);
                Dbf[row * 256 + col] = f2bf(d);
            }
    }
}

// ---------------- K3: fused gather + gelu + GEMM2 + gelu + mean [R9-verbatim] -----
__global__ __launch_bounds__(256) void mlp_kernel(
        const unsigned short* __restrict__ Abf, const unsigned short* __restrict__ Dbf,
        const unsigned short* __restrict__ W2t, const float* __restrict__ b2,
        const int* __restrict__ idx, float* __restrict__ out) {
    __shared__ unsigned short sh[64 * 264];   // padded stride 264
    const int tid = threadIdx.x;
    const int qb  = blockIdx.x << 2;

    // Phase 0: build h1 = gelu(A[nb] + D[gq]) as bf16 in LDS
    {
        const int r   = ((tid >> 6) << 4) | (tid & 15);   // row 0..63 (= qlocal*16+k)
        const int seg = (tid >> 4) & 3;                   // 64-col segment
        const int gq  = qb + (r >> 4);
        const int nb  = idx[(gq << 4) + (r & 15)];
        const unsigned short* arow = Abf + nb * 256 + seg * 64;
        const unsigned short* drow = Dbf + gq * 256 + seg * 64;
        unsigned short* dst = sh + r * 264 + seg * 64;
#pragma unroll
        for (int u = 0; u < 8; ++u) {
            short8 av = *(const short8*)(arow + u * 8);
            short8 dv = *(const short8*)(drow + u * 8);
            short8 hv;
#pragma unroll
            for (int e = 0; e < 8; ++e) {
                float h = bf2f(av[e]) + bf2f(dv[e]);
                hv[e] = (short)f2bf(gelu_fast(h));
            }
            *(short8*)(dst + u * 8) = hv;
        }
    }
    __syncthreads();

    const int lane = tid & 63, wv = tid >> 6;
    const int m = lane & 15, quad = lane >> 4;
    const int ko0 = quad * 8;

    // Phase 2: h2 = gelu(h1 @ W2 + b2)  (64x128 = 4 row-tiles x 2 col-tiles/wave)
    f32x4 acc2[8];
#pragma unroll
    for (int i = 0; i < 8; ++i) acc2[i] = (f32x4){0.f, 0.f, 0.f, 0.f};
#pragma unroll
    for (int ks = 0; ks < 8; ++ks) {
        const int ko = ks * 32 + ko0;
        short8 af[4], bfr[2];
#pragma unroll
        for (int rt = 0; rt < 4; ++rt)
            af[rt] = *(const short8*)(sh + (rt * 16 + m) * 264 + ko);
#pragma unroll
        for (int ct = 0; ct < 2; ++ct)
            bfr[ct] = *(const short8*)(W2t + (wv * 32 + ct * 16 + m) * 256 + ko);
#pragma unroll
        for (int rt = 0; rt < 4; ++rt)
#pragma unroll
            for (int ct = 0; ct < 2; ++ct)
                acc2[rt * 2 + ct] = __builtin_amdgcn_mfma_f32_16x16x32_bf16(
                    af[rt], bfr[ct], acc2[rt * 2 + ct], 0, 0, 0);
    }

    // Epilogue: bias + gelu, mean over K=16, store f32
#pragma unroll
    for (int ct = 0; ct < 2; ++ct) {
        const int col = wv * 32 + ct * 16 + m;
        const float bias = b2[col];
#pragma unroll
        for (int rt = 0; rt < 4; ++rt) {
            float s = 0.f;
#pragma unroll
            for (int j = 0; j < 4; ++j)
                s += gelu_fast(acc2[rt * 2 + ct][j] + bias);
            s += __shfl_xor(s, 16, 64);
            s += __shfl_xor(s, 32, 64);
            if (quad == 0) out[(qb + rt) * 128 + col] = s * 0.0625f;
        }
    }
}

extern "C" void kernel_launch(void* const* d_in, const int* in_sizes, int n_in,
                              void* d_out, int out_size, void* d_ws, size_t ws_size,
                              hipStream_t stream) {
    const float* x      = (const float*)d_in[0];   // (1,8192,128)
    const float* points = (const float*)d_in[1];   // (1,8192,2)
    const float* W1     = (const float*)d_in[2];   // (256,256)
    const float* b1     = (const float*)d_in[3];   // (256,)
    const float* W2     = (const float*)d_in[4];   // (256,128)
    const float* b2     = (const float*)d_in[5];   // (128,)
    float* out = (float*)d_out;

    char* ws = (char*)d_ws;
    unsigned short* W1t = (unsigned short*)ws;                   // 131072 B
    unsigned short* W2t = (unsigned short*)(ws + 131072);        //  65536 B
    int*            idx = (int*)(ws + 196608);                   // 524288 B
    unsigned short* Abf = (unsigned short*)(ws + 720896);        // 4 MiB
    unsigned short* Dbf = (unsigned short*)(ws + 4915200);       // 4 MiB

    knn_kernel<<<2432, 256, 0, stream>>>(points, W1, W2, W1t, W2t, idx);
    gemmAD_kernel<<<256, 256, 0, stream>>>(x, W1t, b1, Abf, Dbf);
    mlp_kernel<<<2048, 256, 0, stream>>>(Abf, Dbf, W2t, b2, idx, out);
}